// Round 12
// baseline (591.179 us; speedup 1.0000x reference)
//
#include <hip/hip_runtime.h>
#include <hip/hip_bf16.h>
#include <hip/hip_fp16.h>

#define N_NODES 50000
#define N_EDGES 800000
#define DD 96
#define NLAYER 4
#define N_GRAPHS 256
#define BN_EPS 1e-5f
#define SLABS 8
#define SFEAT 12        // used halfs per slab row
#define GSU 8           // uints per slab row (32 B)
#define NCHUNK 64
#define CHUNK_E (N_EDGES / NCHUNK)   // 12500
#define NRANGE 4
#define RANGE_N 12544
#define NB_NODE 196     // node blocks of 256

typedef _Float16 half8_t __attribute__((ext_vector_type(8)));
typedef float floatx4 __attribute__((ext_vector_type(4)));

// ---------------- workspace layout (units: 4-byte elements) ----------------
enum : size_t {
  O_CNT    = 0,                        // int[N_NODES]
  O_STATS  = O_CNT + N_NODES,          // float[4*192]
  O_POOL   = O_STATS + 4 * 192,        // float[N_GRAPHS*96]
  O_GCNT   = O_POOL + N_GRAPHS * DD,   // int[N_GRAPHS]
  ZERO_END = O_GCNT + N_GRAPHS,
  O_ROWPTR = ZERO_END,                 // int[N_NODES+1]
  O_DIS    = O_ROWPTR + N_NODES + 1,   // float[N_NODES]
  O_BSUMS  = O_DIS + N_NODES,          // int[256]
  O_PERM   = O_BSUMS + 256,            // int[N_NODES] degree-sorted node ids
  O_DPART  = O_PERM + N_NODES,         // ushort[196][256] degree-bin partials
  O_W16    = O_DPART + NB_NODE * 256 / 2,  // half[4][96][104] fp16 W^T padded
  O_EDGE   = (O_W16 + 4 * 96 * 104 / 2 + 7) & ~size_t(7),  // uint[N_EDGES]
  O_HWH    = (O_EDGE + N_EDGES + 7) & ~size_t(7),     // uint[8][50000][8] = 12.8MB
  O_PART   = O_HWH + (size_t)SLABS * N_NODES * GSU,   // ushort[64][50000]
  O_LOCC   = O_PART + (size_t)NCHUNK * N_NODES / 2,   // ushort[N_EDGES]
  O_P      = O_LOCC + N_EDGES / 2,                    // float[N*96] agg
  WS_ELEMS = O_P + (size_t)N_NODES * DD               // ~44.3 MB
};

__device__ __forceinline__ void atomAddF(float* p, float v) {
  unsafeAtomicAdd(p, v);
}

__device__ __forceinline__ float2 h2f(unsigned int u) {
  __half2 h = *(__half2*)&u;
  return __half22float2(h);
}

// ---------------- CSR build, atomic-free ----------------
__global__ __launch_bounds__(256) void k_phist(const int* __restrict__ dst,
                                               unsigned short* __restrict__ part,
                                               unsigned short* __restrict__ locc) {
  __shared__ int hist[RANGE_N];
  const int b = blockIdx.x;
  const int tid = threadIdx.x;
  const int e0 = b * CHUNK_E, e1 = e0 + CHUNK_E;
  for (int r = 0; r < NRANGE; ++r) {
    const int r0 = r * RANGE_N;
    for (int i = tid; i < RANGE_N; i += 256) hist[i] = 0;
    __syncthreads();
    for (int e = e0 + tid; e < e1; e += 256) {
      unsigned rel = (unsigned)(dst[e] - r0);
      if (rel < RANGE_N) locc[e] = (unsigned short)atomicAdd(&hist[rel], 1);
    }
    __syncthreads();
    for (int i = tid; i < RANGE_N; i += 256) {
      int n = r0 + i;
      if (n < N_NODES) part[(size_t)b * N_NODES + n] = (unsigned short)hist[i];
    }
    __syncthreads();
  }
}

// per node: scan 64 chunk-partials -> offsets; cnt, dis, block sums;
// + per-block degree histogram (for counting sort) + W fp16^T conversion.
__global__ __launch_bounds__(256) void k_reduce(unsigned short* __restrict__ part,
                                                int* __restrict__ cnt,
                                                float* __restrict__ dis,
                                                int* __restrict__ bsums,
                                                unsigned short* __restrict__ dpart,
                                                const float* __restrict__ Wg,
                                                _Float16* __restrict__ W16) {
  __shared__ int s[256];
  __shared__ int dh[256];
  const int tid = threadIdx.x;
  const int n = blockIdx.x * 256 + tid;
  dh[tid] = 0;
  // side job: convert W (4 layers) to fp16 transposed [l][n][k], stride 104
  {
    const int gt = blockIdx.x * 256 + tid;
    const int items = 4 * 96 * 24;  // uint2 items of 4 halfs along k
    for (int i = gt; i < items; i += NB_NODE * 256) {
      int l = i / (96 * 24), rem = i % (96 * 24);
      int nn = rem / 24, k0 = (rem % 24) * 4;
      const float* wl = Wg + (size_t)l * 96 * 96;
      union { _Float16 h[4]; uint2 u; } pk;
      pk.h[0] = (_Float16)wl[(k0 + 0) * 96 + nn];
      pk.h[1] = (_Float16)wl[(k0 + 1) * 96 + nn];
      pk.h[2] = (_Float16)wl[(k0 + 2) * 96 + nn];
      pk.h[3] = (_Float16)wl[(k0 + 3) * 96 + nn];
      *(uint2*)&W16[((size_t)l * 96 + nn) * 104 + k0] = pk.u;
    }
  }
  int run = 0;
  if (n < N_NODES) {
#pragma unroll 8
    for (int b = 0; b < NCHUNK; ++b) {
      size_t idx = (size_t)b * N_NODES + n;
      int t = part[idx];
      part[idx] = (unsigned short)run;
      run += t;
    }
    cnt[n] = run;
    dis[n] = rsqrtf((float)(run + 1));
  }
  __syncthreads();  // dh zero visible
  if (n < N_NODES) atomicAdd(&dh[min(run, 255)], 1);
  s[tid] = (n < N_NODES) ? run : 0;
  __syncthreads();
  dpart[blockIdx.x * 256 + tid] = (unsigned short)dh[tid];
  for (int off = 128; off > 0; off >>= 1) {
    if (tid < off) s[tid] += s[tid + off];
    __syncthreads();
  }
  if (tid == 0) bsums[blockIdx.x] = s[0];
}

__device__ __forceinline__ int lbound(const int* __restrict__ a, int v) {
  int lo = 0, hi = N_NODES;
  while (lo < hi) { int m = (lo + hi) >> 1; if (a[m] < v) lo = m + 1; else hi = m; }
  return lo;
}

// one block: bsums scan + gcnt + degree-bin global offsets (counting sort step 2)
__global__ __launch_bounds__(256) void k_scan_bsums(int* __restrict__ bsums, int nb,
                                                    int* __restrict__ rowptr,
                                                    const int* __restrict__ batch,
                                                    int* __restrict__ gcnt,
                                                    unsigned short* __restrict__ dpart) {
  __shared__ int s[256];
  __shared__ int sb[256];
  int tid = threadIdx.x;
  int v = (tid < nb) ? bsums[tid] : 0;
  s[tid] = v;
  __syncthreads();
  for (int off = 1; off < 256; off <<= 1) {
    int add = (tid >= off) ? s[tid - off] : 0;
    __syncthreads();
    s[tid] += add;
    __syncthreads();
  }
  if (tid < nb) bsums[tid] = s[tid] - v;
  if (tid == 255) rowptr[N_NODES] = s[255];
  gcnt[tid] = lbound(batch, tid + 1) - lbound(batch, tid);
  // degree-bin scan: thread t = bin t; within-bin exclusive over blocks
  int run = 0;
  for (int b = 0; b < NB_NODE; ++b) {
    int t = dpart[b * 256 + tid];
    dpart[b * 256 + tid] = (unsigned short)run;
    run += t;
  }
  sb[tid] = run;
  __syncthreads();
  int mysum = run;
  for (int off = 1; off < 256; off <<= 1) {
    int add = (tid >= off) ? sb[tid - off] : 0;
    __syncthreads();
    sb[tid] += add;
    __syncthreads();
  }
  int binstart = sb[tid] - mysum;  // exclusive bin start
  for (int b = 0; b < NB_NODE; ++b)
    dpart[b * 256 + tid] = (unsigned short)(dpart[b * 256 + tid] + binstart);
}

__global__ __launch_bounds__(256) void k_scan_write(const int* __restrict__ cnt,
                                                    const int* __restrict__ bsums,
                                                    int* __restrict__ rowptr) {
  __shared__ int s[256];
  int i = blockIdx.x * 256 + threadIdx.x;
  int v = (i < N_NODES) ? cnt[i] : 0;
  s[threadIdx.x] = v;
  __syncthreads();
  for (int off = 1; off < 256; off <<= 1) {
    int x = 0;
    if (threadIdx.x >= off) x = s[threadIdx.x - off];
    __syncthreads();
    s[threadIdx.x] += x;
    __syncthreads();
  }
  if (i < N_NODES) rowptr[i] = bsums[blockIdx.x] + s[threadIdx.x] - v;
}

// counting-sort scatter: perm = node ids in ascending-degree order
__global__ __launch_bounds__(256) void k_scatter(const int* __restrict__ cnt,
                                                 const unsigned short* __restrict__ dpart,
                                                 int* __restrict__ perm) {
  __shared__ int h[256];
  const int tid = threadIdx.x;
  h[tid] = 0;
  __syncthreads();
  const int n = blockIdx.x * 256 + tid;
  if (n < N_NODES) {
    int bin = min(cnt[n], 255);
    int r = atomicAdd(&h[bin], 1);
    perm[(int)dpart[blockIdx.x * 256 + bin] + r] = n;
  }
}

__global__ __launch_bounds__(256) void k_fill(const int* __restrict__ ei,
                                              const int* __restrict__ rowptr,
                                              const unsigned short* __restrict__ part,
                                              const unsigned short* __restrict__ locc,
                                              const float* __restrict__ dis,
                                              unsigned int* __restrict__ edg) {
  int e = blockIdx.x * 256 + threadIdx.x;
  if (e >= N_EDGES) return;
  int s = ei[e];
  int d = ei[N_EDGES + e];
  int chunk = e / CHUNK_E;
  int pos = rowptr[d] + (int)part[(size_t)chunk * N_NODES + d] + (int)locc[e];
  unsigned short wb = __half_as_ushort(__float2half_rn(dis[s] * dis[d]));
  edg[pos] = (unsigned int)s | ((unsigned int)wb << 16);
}

// ---------------- GEMM via MFMA fp16 (R11 proven; Wt pre-converted) ----------
__global__ __launch_bounds__(256) void k_gemm(const float* __restrict__ X,
                                              const _Float16* __restrict__ Wh16,
                                              const float* __restrict__ stats,
                                              const float* __restrict__ gamma,
                                              const float* __restrict__ beta,
                                              unsigned int* __restrict__ Yu) {
  __shared__ _Float16 Xh[64 * 104];
  __shared__ _Float16 Wt[96 * 104];
  __shared__ float sA[96], sC[96];
  const int tid = threadIdx.x;
  const int row0 = blockIdx.x * 64;

  if (tid < 96) {
    if (stats) {
      float mu = stats[tid] * (1.f / N_NODES);
      float var = fmaxf(stats[96 + tid] * (1.f / N_NODES) - mu * mu, 0.f);
      float a = gamma[tid] * rsqrtf(var + BN_EPS);
      sA[tid] = a;
      sC[tid] = beta[tid] - mu * a;
    } else {
      sA[tid] = 1.f;
      sC[tid] = 0.f;
    }
  }
  // stage Wt: flat vector copy of 96*104 halfs
  for (int i = tid; i < 96 * 104 / 8; i += 256)
    *(uint4*)&Wt[i * 8] = *(const uint4*)&Wh16[i * 8];
  __syncthreads();
  const bool bn = (stats != nullptr);
  for (int i = tid; i < 64 * 24; i += 256) {
    int r = i / 24, c4 = (i % 24) * 4;
    int gr = row0 + r;
    float4 v = (gr < N_NODES) ? *(const float4*)&X[(size_t)gr * 96 + c4]
                              : make_float4(0.f, 0.f, 0.f, 0.f);
    if (bn) {
      v.x = fmaxf(v.x * sA[c4] + sC[c4], 0.f);
      v.y = fmaxf(v.y * sA[c4 + 1] + sC[c4 + 1], 0.f);
      v.z = fmaxf(v.z * sA[c4 + 2] + sC[c4 + 2], 0.f);
      v.w = fmaxf(v.w * sA[c4 + 3] + sC[c4 + 3], 0.f);
    }
    union { _Float16 h[4]; uint2 u; } pk;
    pk.h[0] = (_Float16)v.x; pk.h[1] = (_Float16)v.y;
    pk.h[2] = (_Float16)v.z; pk.h[3] = (_Float16)v.w;
    *(uint2*)&Xh[r * 104 + c4] = pk.u;
  }
  __syncthreads();

  const int w = tid >> 6, lane = tid & 63;
  const int quad = lane >> 4, l16 = lane & 15;

  half8_t a[3];
#pragma unroll
  for (int kb = 0; kb < 3; ++kb)
    a[kb] = *(const half8_t*)&Xh[(w * 16 + l16) * 104 + kb * 32 + quad * 8];

  floatx4 acc[6];
#pragma unroll
  for (int nt = 0; nt < 6; ++nt) acc[nt] = (floatx4){0.f, 0.f, 0.f, 0.f};
#pragma unroll
  for (int nt = 0; nt < 6; ++nt) {
#pragma unroll
    for (int kb = 0; kb < 3; ++kb) {
      half8_t b = *(const half8_t*)&Wt[(nt * 16 + l16) * 104 + kb * 32 + quad * 8];
      acc[nt] = __builtin_amdgcn_mfma_f32_16x16x32_f16(a[kb], b, acc[nt], 0, 0, 0);
    }
  }

  __syncthreads();
#pragma unroll
  for (int nt = 0; nt < 6; ++nt) {
#pragma unroll
    for (int reg = 0; reg < 4; ++reg) {
      int r = w * 16 + quad * 4 + reg;
      Xh[r * 104 + nt * 16 + l16] = (_Float16)acc[nt][reg];
    }
  }
  __syncthreads();
  for (int i = tid; i < 64 * 24; i += 256) {
    int r = i / 24, rem = i % 24;
    int slab = rem / 3, up = rem % 3;
    int node = row0 + r;
    if (node < N_NODES) {
      uint2 u = *(const uint2*)&Xh[r * 104 + slab * SFEAT + up * 4];
      *(uint2*)&Yu[((size_t)slab * N_NODES + node) * GSU + up * 2] = u;
    }
  }
}

// ---------------- fused aggregation + BN-stats (degree-equalized waves) -------
__global__ __launch_bounds__(256) void k_gather(const unsigned int* __restrict__ hw4,
                                                const int* __restrict__ rowptr,
                                                const unsigned int* __restrict__ edg,
                                                const float* __restrict__ dis,
                                                const int* __restrict__ perm,
                                                float* __restrict__ agg,
                                                float* __restrict__ stats) {
  __shared__ float sred[24];
  const int tid = threadIdx.x;
  const int slab = blockIdx.x & (SLABS - 1);
  const int chunk = blockIdx.x >> 3;
  const int wave = tid >> 6;
  const int lane = tid & 63;
  const int g = lane / 6;      // 0..10 (g==10 -> idle)
  const int ch = lane - g * 6; // uint index 0..5 within row
  const int idx = chunk * 40 + wave * 10 + g;
  const bool valid = (g < 10) && (idx < N_NODES);
  const int nc = valid ? perm[idx] : 0;  // degree-sorted node id

  const unsigned int* slabU = hw4 + (size_t)slab * N_NODES * GSU;

  if (tid < 24) sred[tid] = 0.f;

  const int js = valid ? rowptr[nc] : 0;
  const int je = valid ? rowptr[nc + 1] : 0;

  float a0 = 0.f, a1 = 0.f;
  if (valid) {
    float dn = dis[nc];
    float s2 = dn * dn;  // self-loop weight
    float2 f = h2f(slabU[(size_t)nc * GSU + ch]);
    a0 = f.x * s2;
    a1 = f.y * s2;
  }

  for (int j = js; j < je; j += 8) {
    unsigned int ew[8];
    unsigned int rv[8];
#pragma unroll
    for (int k = 0; k < 8; ++k) {
      int jk = j + k;
      int jc = jk < je ? jk : (je - 1);  // clamp to hot line
      ew[k] = edg[jc];
    }
#pragma unroll
    for (int k = 0; k < 8; ++k)
      rv[k] = slabU[(size_t)(ew[k] & 0xFFFFu) * GSU + ch];
#pragma unroll
    for (int k = 0; k < 8; ++k) {
      float w = (j + k < je)
                    ? __half2float(__ushort_as_half((unsigned short)(ew[k] >> 16)))
                    : 0.f;
      float2 f = h2f(rv[k]);
      a0 = fmaf(w, f.x, a0);
      a1 = fmaf(w, f.y, a1);
    }
  }

  if (valid) {
    *(float2*)&agg[(size_t)nc * DD + slab * SFEAT + ch * 2] = make_float2(a0, a1);
  }

  __syncthreads();
  if (valid) {
    atomicAdd(&sred[ch * 2], a0);
    atomicAdd(&sred[ch * 2 + 1], a1);
    atomicAdd(&sred[12 + ch * 2], a0 * a0);
    atomicAdd(&sred[13 + ch * 2], a1 * a1);
  }
  __syncthreads();
  if (tid < 24) {
    int c = (tid < 12) ? (slab * SFEAT + tid) : (96 + slab * SFEAT + tid - 12);
    atomAddF(&stats[c], sred[tid]);
  }
}

// ---------------- pooling: final BN+ReLU + segment-sum over sorted batch ------
__global__ __launch_bounds__(192) void k_pool(const float* __restrict__ h,
                                              const float* __restrict__ stats,
                                              const float* __restrict__ gamma,
                                              const float* __restrict__ beta,
                                              const int* __restrict__ batch,
                                              float* __restrict__ pool) {
  __shared__ float sA[96], sC[96];
  const int tid = threadIdx.x;
  if (tid < 96) {
    float mu = stats[tid] * (1.f / N_NODES);
    float var = fmaxf(stats[96 + tid] * (1.f / N_NODES) - mu * mu, 0.f);
    float a = gamma[tid] * rsqrtf(var + BN_EPS);
    sA[tid] = a;
    sC[tid] = beta[tid] - mu * a;
  }
  __syncthreads();
  const int chain = blockIdx.x * 8 + tid / 24;
  const int q4 = (tid % 24) * 4;
  int n0 = chain * 32;
  if (n0 >= N_NODES) return;
  int n1 = min(n0 + 32, N_NODES);
  float A0 = sA[q4], A1 = sA[q4 + 1], A2 = sA[q4 + 2], A3 = sA[q4 + 3];
  float C0 = sC[q4], C1 = sC[q4 + 1], C2 = sC[q4 + 2], C3 = sC[q4 + 3];
  int cur = batch[n0];
  float4 acc = make_float4(0.f, 0.f, 0.f, 0.f);
  for (int n = n0; n < n1; ++n) {
    int g = batch[n];
    if (g != cur) {
      float* p = &pool[cur * 96 + q4];
      atomAddF(p, acc.x); atomAddF(p + 1, acc.y);
      atomAddF(p + 2, acc.z); atomAddF(p + 3, acc.w);
      acc = make_float4(0.f, 0.f, 0.f, 0.f);
      cur = g;
    }
    const float4 v = *(const float4*)&h[(size_t)n * 96 + q4];
    acc.x += fmaxf(v.x * A0 + C0, 0.f);
    acc.y += fmaxf(v.y * A1 + C1, 0.f);
    acc.z += fmaxf(v.z * A2 + C2, 0.f);
    acc.w += fmaxf(v.w * A3 + C3, 0.f);
  }
  float* p = &pool[cur * 96 + q4];
  atomAddF(p, acc.x); atomAddF(p + 1, acc.y);
  atomAddF(p + 2, acc.z); atomAddF(p + 3, acc.w);
}

__global__ void k_out(const float* __restrict__ pool, const int* __restrict__ gcnt,
                      float* __restrict__ out) {
  int t = blockIdx.x * blockDim.x + threadIdx.x;
  if (t >= N_GRAPHS * 96) return;
  int g = t / 96;
  int c = gcnt[g];
  if (c < 1) c = 1;
  out[t] = pool[t] / (float)c;
}

extern "C" void kernel_launch(void* const* d_in, const int* in_sizes, int n_in,
                              void* d_out, int out_size, void* d_ws, size_t ws_size,
                              hipStream_t stream) {
  const float* x     = (const float*)d_in[0];
  const int*   ei    = (const int*)d_in[1];
  const int*   batch = (const int*)d_in[2];
  const float* W     = (const float*)d_in[3];
  // d_in[4] = b : cancels exactly through BatchNorm, unused
  const float* gamma = (const float*)d_in[5];
  const float* beta  = (const float*)d_in[6];
  float* out = (float*)d_out;

  float* ws = (float*)d_ws;
  int*   cnt    = (int*)(ws + O_CNT);
  float* stats  = ws + O_STATS;
  float* pool   = ws + O_POOL;
  int*   gcnt   = (int*)(ws + O_GCNT);
  int*   rowptr = (int*)(ws + O_ROWPTR);
  float* dis    = ws + O_DIS;
  int*   bsums  = (int*)(ws + O_BSUMS);
  int*   perm   = (int*)(ws + O_PERM);
  unsigned short* dpart = (unsigned short*)(ws + O_DPART);
  _Float16* W16 = (_Float16*)(ws + O_W16);
  unsigned int* edg = (unsigned int*)(ws + O_EDGE);
  unsigned int* hw4 = (unsigned int*)(ws + O_HWH);
  unsigned short* part = (unsigned short*)(ws + O_PART);
  unsigned short* locc = (unsigned short*)(ws + O_LOCC);
  float* P      = ws + O_P;

  hipMemsetAsync(stats, 0, (ZERO_END - O_STATS) * sizeof(float), stream);

  const int eb = (N_EDGES + 255) / 256;
  k_phist<<<NCHUNK, 256, 0, stream>>>(ei + N_EDGES, part, locc);
  k_reduce<<<NB_NODE, 256, 0, stream>>>(part, cnt, dis, bsums, dpart, W, W16);
  k_scan_bsums<<<1, 256, 0, stream>>>(bsums, NB_NODE, rowptr, batch, gcnt, dpart);
  k_scan_write<<<NB_NODE, 256, 0, stream>>>(cnt, bsums, rowptr);
  k_scatter<<<NB_NODE, 256, 0, stream>>>(cnt, dpart, perm);
  k_fill<<<eb, 256, 0, stream>>>(ei, rowptr, part, locc, dis, edg);

  const int gemmb = (N_NODES + 63) / 64;              // 782
  const int gatherb = SLABS * ((N_NODES + 39) / 40);  // 10000

  const float* hin = x;
  for (int l = 0; l < NLAYER; ++l) {
    const float* st = (l == 0) ? nullptr : (stats + (l - 1) * 192);
    const float* ga = (l == 0) ? nullptr : (gamma + (l - 1) * 96);
    const float* be = (l == 0) ? nullptr : (beta + (l - 1) * 96);
    k_gemm<<<gemmb, 256, 0, stream>>>(hin, W16 + (size_t)l * 96 * 104, st, ga, be, hw4);
    k_gather<<<gatherb, 256, 0, stream>>>(hw4, rowptr, edg, dis, perm, P,
                                          stats + l * 192);
    hin = P;
  }

  const int poolb = ((N_NODES + 31) / 32 + 7) / 8;  // 196
  k_pool<<<poolb, 192, 0, stream>>>(P, stats + 3 * 192, gamma + 3 * 96, beta + 3 * 96,
                                    batch, pool);
  k_out<<<(N_GRAPHS * 96 + 255) / 256, 256, 0, stream>>>(pool, gcnt, out);
}

// Round 13
// 497.983 us; speedup vs baseline: 1.1871x; 1.1871x over previous
//
#include <hip/hip_runtime.h>
#include <hip/hip_bf16.h>
#include <hip/hip_fp16.h>

#define N_NODES 50000
#define N_EDGES 800000
#define DD 96
#define NLAYER 4
#define N_GRAPHS 256
#define BN_EPS 1e-5f
#define SLABS 8
#define SFEAT 12        // used halfs per slab row
#define GSU 8           // uints per slab row (32 B)
#define NCHUNK 64
#define CHUNK_E (N_EDGES / NCHUNK)   // 12500
#define NB_NODE 196     // node blocks of 256
#define PH_RANGES 2
#define PH_RN 25000     // nodes per range
#define PH_HI 12500     // packed int pairs per range (50 KB LDS)
#define PH_NE 49        // max edges per thread (12500/256 rounded up)

typedef _Float16 half8_t __attribute__((ext_vector_type(8)));
typedef float floatx4 __attribute__((ext_vector_type(4)));

// ---------------- workspace layout (units: 4-byte elements) ----------------
enum : size_t {
  O_CNT    = 0,                        // int[N_NODES]
  O_STATS  = O_CNT + N_NODES,          // float[4*192]
  O_POOL   = O_STATS + 4 * 192,        // float[N_GRAPHS*96]
  O_GCNT   = O_POOL + N_GRAPHS * DD,   // int[N_GRAPHS]
  ZERO_END = O_GCNT + N_GRAPHS,
  O_ROWPTR = ZERO_END,                 // int[N_NODES+1]
  O_DIS    = O_ROWPTR + N_NODES + 1,   // float[N_NODES]
  O_BSUMS  = O_DIS + N_NODES,          // int[256]
  O_W16    = O_BSUMS + 256,            // half[4][96][104] fp16 W^T padded
  O_EDGE   = (O_W16 + 4 * 96 * 104 / 2 + 7) & ~size_t(7),  // uint[N_EDGES]
  O_HWH    = (O_EDGE + N_EDGES + 7) & ~size_t(7),     // uint[8][50000][8] = 12.8MB
  O_PART   = O_HWH + (size_t)SLABS * N_NODES * GSU,   // ushort[64][50000]
  O_LOCC   = O_PART + (size_t)NCHUNK * N_NODES / 2,   // ushort[N_EDGES]
  O_P      = O_LOCC + N_EDGES / 2,                    // float[N*96] agg
  WS_ELEMS = O_P + (size_t)N_NODES * DD               // ~44 MB
};

__device__ __forceinline__ void atomAddF(float* p, float v) {
  unsafeAtomicAdd(p, v);
}

__device__ __forceinline__ float2 h2f(unsigned int u) {
  __half2 h = *(__half2*)&u;
  return __half22float2(h);
}

// ---------------- CSR build, atomic-free ----------------
// Single global pass (register-cached dests) + 2 packed-LDS histogram ranges.
// Packed pairs: counter for node 2j in low16 of hist[j], node 2j+1 in high16;
// per-chunk counts <= 12500 so no carry between halves.
__global__ __launch_bounds__(256) void k_phist(const int* __restrict__ dst,
                                               unsigned short* __restrict__ part,
                                               unsigned short* __restrict__ locc) {
  __shared__ int hist[PH_HI];
  const int b = blockIdx.x, tid = threadIdx.x;
  const int e0 = b * CHUNK_E;
  int regs[PH_NE];
#pragma unroll
  for (int i = 0; i < PH_NE; ++i) {
    int e = e0 + tid + i * 256;
    regs[i] = (tid + i * 256 < CHUNK_E) ? dst[e] : -1;  // -1 matches no range
  }
#pragma unroll
  for (int r = 0; r < PH_RANGES; ++r) {
    const int r0 = r * PH_RN;
    for (int i = tid; i < PH_HI; i += 256) hist[i] = 0;
    __syncthreads();
#pragma unroll
    for (int i = 0; i < PH_NE; ++i) {
      unsigned rel = (unsigned)(regs[i] - r0);
      if (rel < PH_RN) {
        int add = (rel & 1) ? (1 << 16) : 1;
        int old = atomicAdd(&hist[rel >> 1], add);
        locc[e0 + tid + i * 256] =
            (unsigned short)((rel & 1) ? (old >> 16) : (old & 0xFFFF));
      }
    }
    __syncthreads();
    for (int i = tid; i < PH_RN; i += 256) {
      int v = hist[i >> 1];
      part[(size_t)b * N_NODES + r0 + i] =
          (unsigned short)((i & 1) ? (v >> 16) : (v & 0xFFFF));
    }
    __syncthreads();
  }
}

// per node: scan 64 chunk-partials -> offsets; cnt, dis, block sums;
// side job: convert W (4 layers) to fp16 transposed [l][n][k], stride 104.
__global__ __launch_bounds__(256) void k_reduce(unsigned short* __restrict__ part,
                                                int* __restrict__ cnt,
                                                float* __restrict__ dis,
                                                int* __restrict__ bsums,
                                                const float* __restrict__ Wg,
                                                _Float16* __restrict__ W16) {
  __shared__ int s[256];
  const int tid = threadIdx.x;
  const int n = blockIdx.x * 256 + tid;
  {
    const int gt = blockIdx.x * 256 + tid;
    const int items = 4 * 96 * 24;  // uint2 items of 4 halfs along k
    for (int i = gt; i < items; i += NB_NODE * 256) {
      int l = i / (96 * 24), rem = i % (96 * 24);
      int nn = rem / 24, k0 = (rem % 24) * 4;
      const float* wl = Wg + (size_t)l * 96 * 96;
      union { _Float16 h[4]; uint2 u; } pk;
      pk.h[0] = (_Float16)wl[(k0 + 0) * 96 + nn];
      pk.h[1] = (_Float16)wl[(k0 + 1) * 96 + nn];
      pk.h[2] = (_Float16)wl[(k0 + 2) * 96 + nn];
      pk.h[3] = (_Float16)wl[(k0 + 3) * 96 + nn];
      *(uint2*)&W16[((size_t)l * 96 + nn) * 104 + k0] = pk.u;
    }
  }
  int run = 0;
  if (n < N_NODES) {
#pragma unroll 8
    for (int b = 0; b < NCHUNK; ++b) {
      size_t idx = (size_t)b * N_NODES + n;
      int t = part[idx];
      part[idx] = (unsigned short)run;
      run += t;
    }
    cnt[n] = run;
    dis[n] = rsqrtf((float)(run + 1));
  }
  s[tid] = (n < N_NODES) ? run : 0;
  __syncthreads();
  for (int off = 128; off > 0; off >>= 1) {
    if (tid < off) s[tid] += s[tid + off];
    __syncthreads();
  }
  if (tid == 0) bsums[blockIdx.x] = s[0];
}

__device__ __forceinline__ int lbound(const int* __restrict__ a, int v) {
  int lo = 0, hi = N_NODES;
  while (lo < hi) { int m = (lo + hi) >> 1; if (a[m] < v) lo = m + 1; else hi = m; }
  return lo;
}

__global__ __launch_bounds__(256) void k_scan_bsums(int* __restrict__ bsums, int nb,
                                                    int* __restrict__ rowptr,
                                                    const int* __restrict__ batch,
                                                    int* __restrict__ gcnt) {
  __shared__ int s[256];
  int tid = threadIdx.x;
  int v = (tid < nb) ? bsums[tid] : 0;
  s[tid] = v;
  __syncthreads();
  for (int off = 1; off < 256; off <<= 1) {
    int add = (tid >= off) ? s[tid - off] : 0;
    __syncthreads();
    s[tid] += add;
    __syncthreads();
  }
  if (tid < nb) bsums[tid] = s[tid] - v;
  if (tid == 255) rowptr[N_NODES] = s[255];
  gcnt[tid] = lbound(batch, tid + 1) - lbound(batch, tid);
}

__global__ __launch_bounds__(256) void k_scan_write(const int* __restrict__ cnt,
                                                    const int* __restrict__ bsums,
                                                    int* __restrict__ rowptr) {
  __shared__ int s[256];
  int i = blockIdx.x * 256 + threadIdx.x;
  int v = (i < N_NODES) ? cnt[i] : 0;
  s[threadIdx.x] = v;
  __syncthreads();
  for (int off = 1; off < 256; off <<= 1) {
    int x = 0;
    if (threadIdx.x >= off) x = s[threadIdx.x - off];
    __syncthreads();
    s[threadIdx.x] += x;
    __syncthreads();
  }
  if (i < N_NODES) rowptr[i] = bsums[blockIdx.x] + s[threadIdx.x] - v;
}

__global__ __launch_bounds__(256) void k_fill(const int* __restrict__ ei,
                                              const int* __restrict__ rowptr,
                                              const unsigned short* __restrict__ part,
                                              const unsigned short* __restrict__ locc,
                                              const float* __restrict__ dis,
                                              unsigned int* __restrict__ edg) {
  int e = blockIdx.x * 256 + threadIdx.x;
  if (e >= N_EDGES) return;
  int s = ei[e];
  int d = ei[N_EDGES + e];
  int chunk = e / CHUNK_E;
  int pos = rowptr[d] + (int)part[(size_t)chunk * N_NODES + d] + (int)locc[e];
  unsigned short wb = __half_as_ushort(__float2half_rn(dis[s] * dis[d]));
  edg[pos] = (unsigned int)s | ((unsigned int)wb << 16);
}

// ---------------- GEMM via MFMA fp16 (R11 proven; Wt pre-converted) ----------
__global__ __launch_bounds__(256) void k_gemm(const float* __restrict__ X,
                                              const _Float16* __restrict__ Wh16,
                                              const float* __restrict__ stats,
                                              const float* __restrict__ gamma,
                                              const float* __restrict__ beta,
                                              unsigned int* __restrict__ Yu) {
  __shared__ _Float16 Xh[64 * 104];
  __shared__ _Float16 Wt[96 * 104];
  __shared__ float sA[96], sC[96];
  const int tid = threadIdx.x;
  const int row0 = blockIdx.x * 64;

  if (tid < 96) {
    if (stats) {
      float mu = stats[tid] * (1.f / N_NODES);
      float var = fmaxf(stats[96 + tid] * (1.f / N_NODES) - mu * mu, 0.f);
      float a = gamma[tid] * rsqrtf(var + BN_EPS);
      sA[tid] = a;
      sC[tid] = beta[tid] - mu * a;
    } else {
      sA[tid] = 1.f;
      sC[tid] = 0.f;
    }
  }
  for (int i = tid; i < 96 * 104 / 8; i += 256)
    *(uint4*)&Wt[i * 8] = *(const uint4*)&Wh16[i * 8];
  __syncthreads();
  const bool bn = (stats != nullptr);
  for (int i = tid; i < 64 * 24; i += 256) {
    int r = i / 24, c4 = (i % 24) * 4;
    int gr = row0 + r;
    float4 v = (gr < N_NODES) ? *(const float4*)&X[(size_t)gr * 96 + c4]
                              : make_float4(0.f, 0.f, 0.f, 0.f);
    if (bn) {
      v.x = fmaxf(v.x * sA[c4] + sC[c4], 0.f);
      v.y = fmaxf(v.y * sA[c4 + 1] + sC[c4 + 1], 0.f);
      v.z = fmaxf(v.z * sA[c4 + 2] + sC[c4 + 2], 0.f);
      v.w = fmaxf(v.w * sA[c4 + 3] + sC[c4 + 3], 0.f);
    }
    union { _Float16 h[4]; uint2 u; } pk;
    pk.h[0] = (_Float16)v.x; pk.h[1] = (_Float16)v.y;
    pk.h[2] = (_Float16)v.z; pk.h[3] = (_Float16)v.w;
    *(uint2*)&Xh[r * 104 + c4] = pk.u;
  }
  __syncthreads();

  const int w = tid >> 6, lane = tid & 63;
  const int quad = lane >> 4, l16 = lane & 15;

  half8_t a[3];
#pragma unroll
  for (int kb = 0; kb < 3; ++kb)
    a[kb] = *(const half8_t*)&Xh[(w * 16 + l16) * 104 + kb * 32 + quad * 8];

  floatx4 acc[6];
#pragma unroll
  for (int nt = 0; nt < 6; ++nt) acc[nt] = (floatx4){0.f, 0.f, 0.f, 0.f};
#pragma unroll
  for (int nt = 0; nt < 6; ++nt) {
#pragma unroll
    for (int kb = 0; kb < 3; ++kb) {
      half8_t b = *(const half8_t*)&Wt[(nt * 16 + l16) * 104 + kb * 32 + quad * 8];
      acc[nt] = __builtin_amdgcn_mfma_f32_16x16x32_f16(a[kb], b, acc[nt], 0, 0, 0);
    }
  }

  __syncthreads();
#pragma unroll
  for (int nt = 0; nt < 6; ++nt) {
#pragma unroll
    for (int reg = 0; reg < 4; ++reg) {
      int r = w * 16 + quad * 4 + reg;
      Xh[r * 104 + nt * 16 + l16] = (_Float16)acc[nt][reg];
    }
  }
  __syncthreads();
  for (int i = tid; i < 64 * 24; i += 256) {
    int r = i / 24, rem = i % 24;
    int slab = rem / 3, up = rem % 3;
    int node = row0 + r;
    if (node < N_NODES) {
      uint2 u = *(const uint2*)&Xh[r * 104 + slab * SFEAT + up * 4];
      *(uint2*)&Yu[((size_t)slab * N_NODES + node) * GSU + up * 2] = u;
    }
  }
}

// ---------------- fused aggregation + BN-stats (R11 champion config) ----------
__global__ __launch_bounds__(256) void k_gather(const unsigned int* __restrict__ hw4,
                                                const int* __restrict__ rowptr,
                                                const unsigned int* __restrict__ edg,
                                                const float* __restrict__ dis,
                                                float* __restrict__ agg,
                                                float* __restrict__ stats) {
  __shared__ float sred[24];
  const int tid = threadIdx.x;
  const int slab = blockIdx.x & (SLABS - 1);
  const int chunk = blockIdx.x >> 3;
  const int wave = tid >> 6;
  const int lane = tid & 63;
  const int g = lane / 6;      // 0..10 (g==10 -> idle)
  const int ch = lane - g * 6; // uint index 0..5 within row
  const int n = chunk * 40 + wave * 10 + g;
  const bool valid = (g < 10) && (n < N_NODES);
  const int nc = valid ? n : 0;

  const unsigned int* slabU = hw4 + (size_t)slab * N_NODES * GSU;

  if (tid < 24) sred[tid] = 0.f;

  const int js = valid ? rowptr[nc] : 0;
  const int je = valid ? rowptr[nc + 1] : 0;

  float a0 = 0.f, a1 = 0.f;
  if (valid) {
    float dn = dis[nc];
    float s2 = dn * dn;  // self-loop weight
    float2 f = h2f(slabU[(size_t)nc * GSU + ch]);
    a0 = f.x * s2;
    a1 = f.y * s2;
  }

  for (int j = js; j < je; j += 8) {
    unsigned int ew[8];
    unsigned int rv[8];
#pragma unroll
    for (int k = 0; k < 8; ++k) {
      int jk = j + k;
      int jc = jk < je ? jk : (je - 1);  // clamp to hot line
      ew[k] = edg[jc];
    }
#pragma unroll
    for (int k = 0; k < 8; ++k)
      rv[k] = slabU[(size_t)(ew[k] & 0xFFFFu) * GSU + ch];
#pragma unroll
    for (int k = 0; k < 8; ++k) {
      float w = (j + k < je)
                    ? __half2float(__ushort_as_half((unsigned short)(ew[k] >> 16)))
                    : 0.f;
      float2 f = h2f(rv[k]);
      a0 = fmaf(w, f.x, a0);
      a1 = fmaf(w, f.y, a1);
    }
  }

  if (valid) {
    *(float2*)&agg[(size_t)n * DD + slab * SFEAT + ch * 2] = make_float2(a0, a1);
  }

  __syncthreads();
  if (valid) {
    atomicAdd(&sred[ch * 2], a0);
    atomicAdd(&sred[ch * 2 + 1], a1);
    atomicAdd(&sred[12 + ch * 2], a0 * a0);
    atomicAdd(&sred[13 + ch * 2], a1 * a1);
  }
  __syncthreads();
  if (tid < 24) {
    int c = (tid < 12) ? (slab * SFEAT + tid) : (96 + slab * SFEAT + tid - 12);
    atomAddF(&stats[c], sred[tid]);
  }
}

// ---------------- pooling: final BN+ReLU + segment-sum over sorted batch ------
__global__ __launch_bounds__(192) void k_pool(const float* __restrict__ h,
                                              const float* __restrict__ stats,
                                              const float* __restrict__ gamma,
                                              const float* __restrict__ beta,
                                              const int* __restrict__ batch,
                                              float* __restrict__ pool) {
  __shared__ float sA[96], sC[96];
  const int tid = threadIdx.x;
  if (tid < 96) {
    float mu = stats[tid] * (1.f / N_NODES);
    float var = fmaxf(stats[96 + tid] * (1.f / N_NODES) - mu * mu, 0.f);
    float a = gamma[tid] * rsqrtf(var + BN_EPS);
    sA[tid] = a;
    sC[tid] = beta[tid] - mu * a;
  }
  __syncthreads();
  const int chain = blockIdx.x * 8 + tid / 24;
  const int q4 = (tid % 24) * 4;
  int n0 = chain * 32;
  if (n0 >= N_NODES) return;
  int n1 = min(n0 + 32, N_NODES);
  float A0 = sA[q4], A1 = sA[q4 + 1], A2 = sA[q4 + 2], A3 = sA[q4 + 3];
  float C0 = sC[q4], C1 = sC[q4 + 1], C2 = sC[q4 + 2], C3 = sC[q4 + 3];
  int cur = batch[n0];
  float4 acc = make_float4(0.f, 0.f, 0.f, 0.f);
  for (int n = n0; n < n1; ++n) {
    int g = batch[n];
    if (g != cur) {
      float* p = &pool[cur * 96 + q4];
      atomAddF(p, acc.x); atomAddF(p + 1, acc.y);
      atomAddF(p + 2, acc.z); atomAddF(p + 3, acc.w);
      acc = make_float4(0.f, 0.f, 0.f, 0.f);
      cur = g;
    }
    const float4 v = *(const float4*)&h[(size_t)n * 96 + q4];
    acc.x += fmaxf(v.x * A0 + C0, 0.f);
    acc.y += fmaxf(v.y * A1 + C1, 0.f);
    acc.z += fmaxf(v.z * A2 + C2, 0.f);
    acc.w += fmaxf(v.w * A3 + C3, 0.f);
  }
  float* p = &pool[cur * 96 + q4];
  atomAddF(p, acc.x); atomAddF(p + 1, acc.y);
  atomAddF(p + 2, acc.z); atomAddF(p + 3, acc.w);
}

__global__ void k_out(const float* __restrict__ pool, const int* __restrict__ gcnt,
                      float* __restrict__ out) {
  int t = blockIdx.x * blockDim.x + threadIdx.x;
  if (t >= N_GRAPHS * 96) return;
  int g = t / 96;
  int c = gcnt[g];
  if (c < 1) c = 1;
  out[t] = pool[t] / (float)c;
}

extern "C" void kernel_launch(void* const* d_in, const int* in_sizes, int n_in,
                              void* d_out, int out_size, void* d_ws, size_t ws_size,
                              hipStream_t stream) {
  const float* x     = (const float*)d_in[0];
  const int*   ei    = (const int*)d_in[1];
  const int*   batch = (const int*)d_in[2];
  const float* W     = (const float*)d_in[3];
  // d_in[4] = b : cancels exactly through BatchNorm, unused
  const float* gamma = (const float*)d_in[5];
  const float* beta  = (const float*)d_in[6];
  float* out = (float*)d_out;

  float* ws = (float*)d_ws;
  int*   cnt    = (int*)(ws + O_CNT);
  float* stats  = ws + O_STATS;
  float* pool   = ws + O_POOL;
  int*   gcnt   = (int*)(ws + O_GCNT);
  int*   rowptr = (int*)(ws + O_ROWPTR);
  float* dis    = ws + O_DIS;
  int*   bsums  = (int*)(ws + O_BSUMS);
  _Float16* W16 = (_Float16*)(ws + O_W16);
  unsigned int* edg = (unsigned int*)(ws + O_EDGE);
  unsigned int* hw4 = (unsigned int*)(ws + O_HWH);
  unsigned short* part = (unsigned short*)(ws + O_PART);
  unsigned short* locc = (unsigned short*)(ws + O_LOCC);
  float* P      = ws + O_P;

  hipMemsetAsync(stats, 0, (ZERO_END - O_STATS) * sizeof(float), stream);

  const int eb = (N_EDGES + 255) / 256;
  k_phist<<<NCHUNK, 256, 0, stream>>>(ei + N_EDGES, part, locc);
  k_reduce<<<NB_NODE, 256, 0, stream>>>(part, cnt, dis, bsums, W, W16);
  k_scan_bsums<<<1, 256, 0, stream>>>(bsums, NB_NODE, rowptr, batch, gcnt);
  k_scan_write<<<NB_NODE, 256, 0, stream>>>(cnt, bsums, rowptr);
  k_fill<<<eb, 256, 0, stream>>>(ei, rowptr, part, locc, dis, edg);

  const int gemmb = (N_NODES + 63) / 64;              // 782
  const int gatherb = SLABS * ((N_NODES + 39) / 40);  // 10000

  const float* hin = x;
  for (int l = 0; l < NLAYER; ++l) {
    const float* st = (l == 0) ? nullptr : (stats + (l - 1) * 192);
    const float* ga = (l == 0) ? nullptr : (gamma + (l - 1) * 96);
    const float* be = (l == 0) ? nullptr : (beta + (l - 1) * 96);
    k_gemm<<<gemmb, 256, 0, stream>>>(hin, W16 + (size_t)l * 96 * 104, st, ga, be, hw4);
    k_gather<<<gatherb, 256, 0, stream>>>(hw4, rowptr, edg, dis, P, stats + l * 192);
    hin = P;
  }

  const int poolb = ((N_NODES + 31) / 32 + 7) / 8;  // 196
  k_pool<<<poolb, 192, 0, stream>>>(P, stats + 3 * 192, gamma + 3 * 96, beta + 3 * 96,
                                    batch, pool);
  k_out<<<(N_GRAPHS * 96 + 255) / 256, 256, 0, stream>>>(pool, gcnt, out);
}

// Round 14
// 487.010 us; speedup vs baseline: 1.2139x; 1.0225x over previous
//
#include <hip/hip_runtime.h>
#include <hip/hip_bf16.h>
#include <hip/hip_fp16.h>

#define N_NODES 50000
#define N_EDGES 800000
#define DD 96
#define NLAYER 4
#define N_GRAPHS 256
#define BN_EPS 1e-5f
#define SLABS 8
#define SFEAT 12        // used halfs per slab row of hw
#define GSU 8           // uints per hw slab row (32 B)
#define AGU 6           // uints per agg slab row (24 B fp16)
#define NCHUNK 64
#define CHUNK_E (N_EDGES / NCHUNK)   // 12500
#define NB_NODE 196
#define PH_RANGES 2
#define PH_RN 25000
#define PH_HI 12500
#define PH_NE 49

typedef _Float16 half8_t __attribute__((ext_vector_type(8)));
typedef float floatx4 __attribute__((ext_vector_type(4)));

// ---------------- workspace layout (units: 4-byte elements) ----------------
enum : size_t {
  O_CNT    = 0,                        // int[N_NODES]
  O_STATS  = O_CNT + N_NODES,          // float[4*192]
  O_POOL   = O_STATS + 4 * 192,        // float[N_GRAPHS*96]
  O_GCNT   = O_POOL + N_GRAPHS * DD,   // int[N_GRAPHS]
  ZERO_END = O_GCNT + N_GRAPHS,
  O_ROWPTR = ZERO_END,                 // int[N_NODES+1]
  O_DIS    = O_ROWPTR + N_NODES + 1,   // float[N_NODES]
  O_BSUMS  = O_DIS + N_NODES,          // int[256]
  O_W16    = O_BSUMS + 256,            // half[4][96][104] fp16 W^T padded
  O_EDGE   = (O_W16 + 4 * 96 * 104 / 2 + 7) & ~size_t(7),  // uint[N_EDGES]
  O_HWH    = (O_EDGE + N_EDGES + 7) & ~size_t(7),     // uint[8][50000][8] = 12.8MB
  O_PART   = O_HWH + (size_t)SLABS * N_NODES * GSU,   // ushort[64][50000]
  O_LOCC   = O_PART + (size_t)NCHUNK * N_NODES / 2,   // ushort[N_EDGES]
  O_P      = O_LOCC + N_EDGES / 2,                    // uint[8][50000][6] fp16 agg
  WS_ELEMS = O_P + (size_t)SLABS * N_NODES * AGU      // ~35 MB
};

__device__ __forceinline__ void atomAddF(float* p, float v) {
  unsafeAtomicAdd(p, v);
}

__device__ __forceinline__ float2 h2f(unsigned int u) {
  __half2 h = *(__half2*)&u;
  return __half22float2(h);
}

// ---------------- CSR build, atomic-free (R13 proven) ----------------
__global__ __launch_bounds__(256) void k_phist(const int* __restrict__ dst,
                                               unsigned short* __restrict__ part,
                                               unsigned short* __restrict__ locc,
                                               float* __restrict__ zbase) {
  __shared__ int hist[PH_HI];
  const int b = blockIdx.x, tid = threadIdx.x;
  const int e0 = b * CHUNK_E;
  // fold: block 0 zeros stats/pool/gcnt (replaces hipMemsetAsync dispatch)
  if (b == 0) {
    for (int i = tid; i < (int)(ZERO_END - O_STATS); i += 256) zbase[i] = 0.f;
  }
  int regs[PH_NE];
#pragma unroll
  for (int i = 0; i < PH_NE; ++i) {
    int e = e0 + tid + i * 256;
    regs[i] = (tid + i * 256 < CHUNK_E) ? dst[e] : -1;
  }
#pragma unroll
  for (int r = 0; r < PH_RANGES; ++r) {
    const int r0 = r * PH_RN;
    for (int i = tid; i < PH_HI; i += 256) hist[i] = 0;
    __syncthreads();
#pragma unroll
    for (int i = 0; i < PH_NE; ++i) {
      unsigned rel = (unsigned)(regs[i] - r0);
      if (rel < PH_RN) {
        int add = (rel & 1) ? (1 << 16) : 1;
        int old = atomicAdd(&hist[rel >> 1], add);
        locc[e0 + tid + i * 256] =
            (unsigned short)((rel & 1) ? (old >> 16) : (old & 0xFFFF));
      }
    }
    __syncthreads();
    for (int i = tid; i < PH_RN; i += 256) {
      int v = hist[i >> 1];
      part[(size_t)b * N_NODES + r0 + i] =
          (unsigned short)((i & 1) ? (v >> 16) : (v & 0xFFFF));
    }
    __syncthreads();
  }
}

__global__ __launch_bounds__(256) void k_reduce(unsigned short* __restrict__ part,
                                                int* __restrict__ cnt,
                                                float* __restrict__ dis,
                                                int* __restrict__ bsums,
                                                const float* __restrict__ Wg,
                                                _Float16* __restrict__ W16) {
  __shared__ int s[256];
  const int tid = threadIdx.x;
  const int n = blockIdx.x * 256 + tid;
  {
    const int gt = blockIdx.x * 256 + tid;
    const int items = 4 * 96 * 24;
    for (int i = gt; i < items; i += NB_NODE * 256) {
      int l = i / (96 * 24), rem = i % (96 * 24);
      int nn = rem / 24, k0 = (rem % 24) * 4;
      const float* wl = Wg + (size_t)l * 96 * 96;
      union { _Float16 h[4]; uint2 u; } pk;
      pk.h[0] = (_Float16)wl[(k0 + 0) * 96 + nn];
      pk.h[1] = (_Float16)wl[(k0 + 1) * 96 + nn];
      pk.h[2] = (_Float16)wl[(k0 + 2) * 96 + nn];
      pk.h[3] = (_Float16)wl[(k0 + 3) * 96 + nn];
      *(uint2*)&W16[((size_t)l * 96 + nn) * 104 + k0] = pk.u;
    }
  }
  int run = 0;
  if (n < N_NODES) {
#pragma unroll 8
    for (int b = 0; b < NCHUNK; ++b) {
      size_t idx = (size_t)b * N_NODES + n;
      int t = part[idx];
      part[idx] = (unsigned short)run;
      run += t;
    }
    cnt[n] = run;
    dis[n] = rsqrtf((float)(run + 1));
  }
  s[tid] = (n < N_NODES) ? run : 0;
  __syncthreads();
  for (int off = 128; off > 0; off >>= 1) {
    if (tid < off) s[tid] += s[tid + off];
    __syncthreads();
  }
  if (tid == 0) bsums[blockIdx.x] = s[0];
}

__device__ __forceinline__ int lbound(const int* __restrict__ a, int v) {
  int lo = 0, hi = N_NODES;
  while (lo < hi) { int m = (lo + hi) >> 1; if (a[m] < v) lo = m + 1; else hi = m; }
  return lo;
}

__global__ __launch_bounds__(256) void k_scan_bsums(int* __restrict__ bsums, int nb,
                                                    int* __restrict__ rowptr,
                                                    const int* __restrict__ batch,
                                                    int* __restrict__ gcnt) {
  __shared__ int s[256];
  int tid = threadIdx.x;
  int v = (tid < nb) ? bsums[tid] : 0;
  s[tid] = v;
  __syncthreads();
  for (int off = 1; off < 256; off <<= 1) {
    int add = (tid >= off) ? s[tid - off] : 0;
    __syncthreads();
    s[tid] += add;
    __syncthreads();
  }
  if (tid < nb) bsums[tid] = s[tid] - v;
  if (tid == 255) rowptr[N_NODES] = s[255];
  gcnt[tid] = lbound(batch, tid + 1) - lbound(batch, tid);
}

__global__ __launch_bounds__(256) void k_scan_write(const int* __restrict__ cnt,
                                                    const int* __restrict__ bsums,
                                                    int* __restrict__ rowptr) {
  __shared__ int s[256];
  int i = blockIdx.x * 256 + threadIdx.x;
  int v = (i < N_NODES) ? cnt[i] : 0;
  s[threadIdx.x] = v;
  __syncthreads();
  for (int off = 1; off < 256; off <<= 1) {
    int x = 0;
    if (threadIdx.x >= off) x = s[threadIdx.x - off];
    __syncthreads();
    s[threadIdx.x] += x;
    __syncthreads();
  }
  if (i < N_NODES) rowptr[i] = bsums[blockIdx.x] + s[threadIdx.x] - v;
}

__global__ __launch_bounds__(256) void k_fill(const int* __restrict__ ei,
                                              const int* __restrict__ rowptr,
                                              const unsigned short* __restrict__ part,
                                              const unsigned short* __restrict__ locc,
                                              const float* __restrict__ dis,
                                              unsigned int* __restrict__ edg) {
  int e = blockIdx.x * 256 + threadIdx.x;
  if (e >= N_EDGES) return;
  int s = ei[e];
  int d = ei[N_EDGES + e];
  int chunk = e / CHUNK_E;
  int pos = rowptr[d] + (int)part[(size_t)chunk * N_NODES + d] + (int)locc[e];
  unsigned short wb = __half_as_ushort(__float2half_rn(dis[s] * dis[d]));
  edg[pos] = (unsigned int)s | ((unsigned int)wb << 16);
}

// ---------------- GEMM via MFMA fp16; X from fp32 (l=0) or fp16 agg (l>0) -----
__global__ __launch_bounds__(256) void k_gemm(const float* __restrict__ X32,
                                              const unsigned int* __restrict__ X16,
                                              const _Float16* __restrict__ Wh16,
                                              const float* __restrict__ stats,
                                              const float* __restrict__ gamma,
                                              const float* __restrict__ beta,
                                              unsigned int* __restrict__ Yu) {
  __shared__ _Float16 Xh[64 * 104];
  __shared__ _Float16 Wt[96 * 104];
  __shared__ float sA[96], sC[96];
  const int tid = threadIdx.x;
  const int row0 = blockIdx.x * 64;

  if (tid < 96) {
    if (stats) {
      float mu = stats[tid] * (1.f / N_NODES);
      float var = fmaxf(stats[96 + tid] * (1.f / N_NODES) - mu * mu, 0.f);
      float a = gamma[tid] * rsqrtf(var + BN_EPS);
      sA[tid] = a;
      sC[tid] = beta[tid] - mu * a;
    } else {
      sA[tid] = 1.f;
      sC[tid] = 0.f;
    }
  }
  for (int i = tid; i < 96 * 104 / 8; i += 256)
    *(uint4*)&Wt[i * 8] = *(const uint4*)&Wh16[i * 8];
  __syncthreads();
  const bool bn = (stats != nullptr);
  for (int i = tid; i < 64 * 24; i += 256) {
    int r = i / 24, j = i % 24;
    int c4 = j * 4;
    int gr = row0 + r;
    float4 v = make_float4(0.f, 0.f, 0.f, 0.f);
    if (gr < N_NODES) {
      if (X16) {
        // slab-major fp16 agg: slab = j/3, uint2 part = j%3
        int slab = j / 3, pt = j % 3;
        uint2 u = *(const uint2*)&X16[((size_t)slab * N_NODES + gr) * AGU + pt * 2];
        float2 f01 = h2f(u.x), f23 = h2f(u.y);
        v = make_float4(f01.x, f01.y, f23.x, f23.y);
      } else {
        v = *(const float4*)&X32[(size_t)gr * 96 + c4];
      }
    }
    if (bn) {
      v.x = fmaxf(v.x * sA[c4] + sC[c4], 0.f);
      v.y = fmaxf(v.y * sA[c4 + 1] + sC[c4 + 1], 0.f);
      v.z = fmaxf(v.z * sA[c4 + 2] + sC[c4 + 2], 0.f);
      v.w = fmaxf(v.w * sA[c4 + 3] + sC[c4 + 3], 0.f);
    }
    union { _Float16 h[4]; uint2 u; } pk;
    pk.h[0] = (_Float16)v.x; pk.h[1] = (_Float16)v.y;
    pk.h[2] = (_Float16)v.z; pk.h[3] = (_Float16)v.w;
    *(uint2*)&Xh[r * 104 + c4] = pk.u;
  }
  __syncthreads();

  const int w = tid >> 6, lane = tid & 63;
  const int quad = lane >> 4, l16 = lane & 15;

  half8_t a[3];
#pragma unroll
  for (int kb = 0; kb < 3; ++kb)
    a[kb] = *(const half8_t*)&Xh[(w * 16 + l16) * 104 + kb * 32 + quad * 8];

  floatx4 acc[6];
#pragma unroll
  for (int nt = 0; nt < 6; ++nt) acc[nt] = (floatx4){0.f, 0.f, 0.f, 0.f};
#pragma unroll
  for (int nt = 0; nt < 6; ++nt) {
#pragma unroll
    for (int kb = 0; kb < 3; ++kb) {
      half8_t b = *(const half8_t*)&Wt[(nt * 16 + l16) * 104 + kb * 32 + quad * 8];
      acc[nt] = __builtin_amdgcn_mfma_f32_16x16x32_f16(a[kb], b, acc[nt], 0, 0, 0);
    }
  }

  __syncthreads();
#pragma unroll
  for (int nt = 0; nt < 6; ++nt) {
#pragma unroll
    for (int reg = 0; reg < 4; ++reg) {
      int r = w * 16 + quad * 4 + reg;
      Xh[r * 104 + nt * 16 + l16] = (_Float16)acc[nt][reg];
    }
  }
  __syncthreads();
  for (int i = tid; i < 64 * 24; i += 256) {
    int r = i / 24, rem = i % 24;
    int slab = rem / 3, up = rem % 3;
    int node = row0 + r;
    if (node < N_NODES) {
      uint2 u = *(const uint2*)&Xh[r * 104 + slab * SFEAT + up * 4];
      *(uint2*)&Yu[((size_t)slab * N_NODES + node) * GSU + up * 2] = u;
    }
  }
}

// ---------------- fused aggregation + BN-stats (fp16 slab-major agg out) ------
__global__ __launch_bounds__(256) void k_gather(const unsigned int* __restrict__ hw4,
                                                const int* __restrict__ rowptr,
                                                const unsigned int* __restrict__ edg,
                                                const float* __restrict__ dis,
                                                unsigned int* __restrict__ aggu,
                                                float* __restrict__ stats) {
  __shared__ float sred[24];
  const int tid = threadIdx.x;
  const int slab = blockIdx.x & (SLABS - 1);
  const int chunk = blockIdx.x >> 3;
  const int wave = tid >> 6;
  const int lane = tid & 63;
  const int g = lane / 6;      // 0..10 (g==10 -> idle)
  const int ch = lane - g * 6; // uint index 0..5
  const int n = chunk * 40 + wave * 10 + g;
  const bool valid = (g < 10) && (n < N_NODES);
  const int nc = valid ? n : 0;

  const unsigned int* slabU = hw4 + (size_t)slab * N_NODES * GSU;

  if (tid < 24) sred[tid] = 0.f;

  const int js = valid ? rowptr[nc] : 0;
  const int je = valid ? rowptr[nc + 1] : 0;

  float a0 = 0.f, a1 = 0.f;
  if (valid) {
    float dn = dis[nc];
    float s2 = dn * dn;  // self-loop weight
    float2 f = h2f(slabU[(size_t)nc * GSU + ch]);
    a0 = f.x * s2;
    a1 = f.y * s2;
  }

  for (int j = js; j < je; j += 8) {
    unsigned int ew[8];
    unsigned int rv[8];
#pragma unroll
    for (int k = 0; k < 8; ++k) {
      int jk = j + k;
      int jc = jk < je ? jk : (je - 1);  // clamp to hot line
      ew[k] = edg[jc];
    }
#pragma unroll
    for (int k = 0; k < 8; ++k)
      rv[k] = slabU[(size_t)(ew[k] & 0xFFFFu) * GSU + ch];
#pragma unroll
    for (int k = 0; k < 8; ++k) {
      float w = (j + k < je)
                    ? __half2float(__ushort_as_half((unsigned short)(ew[k] >> 16)))
                    : 0.f;
      float2 f = h2f(rv[k]);
      a0 = fmaf(w, f.x, a0);
      a1 = fmaf(w, f.y, a1);
    }
  }

  if (valid) {
    __half2 p = __floats2half2_rn(a0, a1);
    aggu[((size_t)slab * N_NODES + n) * AGU + ch] = *(unsigned int*)&p;
  }

  __syncthreads();
  if (valid) {
    atomicAdd(&sred[ch * 2], a0);
    atomicAdd(&sred[ch * 2 + 1], a1);
    atomicAdd(&sred[12 + ch * 2], a0 * a0);
    atomicAdd(&sred[13 + ch * 2], a1 * a1);
  }
  __syncthreads();
  if (tid < 24) {
    int c = (tid < 12) ? (slab * SFEAT + tid) : (96 + slab * SFEAT + tid - 12);
    atomAddF(&stats[c], sred[tid]);
  }
}

// ---------------- pooling: final BN+ReLU + segment-sum (fp16 agg input) -------
__global__ __launch_bounds__(192) void k_pool(const unsigned int* __restrict__ hu,
                                              const float* __restrict__ stats,
                                              const float* __restrict__ gamma,
                                              const float* __restrict__ beta,
                                              const int* __restrict__ batch,
                                              float* __restrict__ pool) {
  __shared__ float sA[96], sC[96];
  const int tid = threadIdx.x;
  if (tid < 96) {
    float mu = stats[tid] * (1.f / N_NODES);
    float var = fmaxf(stats[96 + tid] * (1.f / N_NODES) - mu * mu, 0.f);
    float a = gamma[tid] * rsqrtf(var + BN_EPS);
    sA[tid] = a;
    sC[tid] = beta[tid] - mu * a;
  }
  __syncthreads();
  const int chain = blockIdx.x * 8 + tid / 24;
  const int j = tid % 24;         // uint2 index within 96 ch
  const int q4 = j * 4;
  const int slab = j / 3, pt = j % 3;
  int n0 = chain * 32;
  if (n0 >= N_NODES) return;
  int n1 = min(n0 + 32, N_NODES);
  float A0 = sA[q4], A1 = sA[q4 + 1], A2 = sA[q4 + 2], A3 = sA[q4 + 3];
  float C0 = sC[q4], C1 = sC[q4 + 1], C2 = sC[q4 + 2], C3 = sC[q4 + 3];
  const unsigned int* base = hu + (size_t)slab * N_NODES * AGU + pt * 2;
  int cur = batch[n0];
  float4 acc = make_float4(0.f, 0.f, 0.f, 0.f);
  for (int n = n0; n < n1; ++n) {
    int g = batch[n];
    if (g != cur) {
      float* p = &pool[cur * 96 + q4];
      atomAddF(p, acc.x); atomAddF(p + 1, acc.y);
      atomAddF(p + 2, acc.z); atomAddF(p + 3, acc.w);
      acc = make_float4(0.f, 0.f, 0.f, 0.f);
      cur = g;
    }
    uint2 u = *(const uint2*)&base[(size_t)n * AGU];
    float2 f01 = h2f(u.x), f23 = h2f(u.y);
    acc.x += fmaxf(f01.x * A0 + C0, 0.f);
    acc.y += fmaxf(f01.y * A1 + C1, 0.f);
    acc.z += fmaxf(f23.x * A2 + C2, 0.f);
    acc.w += fmaxf(f23.y * A3 + C3, 0.f);
  }
  float* p = &pool[cur * 96 + q4];
  atomAddF(p, acc.x); atomAddF(p + 1, acc.y);
  atomAddF(p + 2, acc.z); atomAddF(p + 3, acc.w);
}

__global__ void k_out(const float* __restrict__ pool, const int* __restrict__ gcnt,
                      float* __restrict__ out) {
  int t = blockIdx.x * blockDim.x + threadIdx.x;
  if (t >= N_GRAPHS * 96) return;
  int g = t / 96;
  int c = gcnt[g];
  if (c < 1) c = 1;
  out[t] = pool[t] / (float)c;
}

extern "C" void kernel_launch(void* const* d_in, const int* in_sizes, int n_in,
                              void* d_out, int out_size, void* d_ws, size_t ws_size,
                              hipStream_t stream) {
  const float* x     = (const float*)d_in[0];
  const int*   ei    = (const int*)d_in[1];
  const int*   batch = (const int*)d_in[2];
  const float* W     = (const float*)d_in[3];
  // d_in[4] = b : cancels exactly through BatchNorm, unused
  const float* gamma = (const float*)d_in[5];
  const float* beta  = (const float*)d_in[6];
  float* out = (float*)d_out;

  float* ws = (float*)d_ws;
  int*   cnt    = (int*)(ws + O_CNT);
  float* stats  = ws + O_STATS;
  float* pool   = ws + O_POOL;
  int*   gcnt   = (int*)(ws + O_GCNT);
  int*   rowptr = (int*)(ws + O_ROWPTR);
  float* dis    = ws + O_DIS;
  int*   bsums  = (int*)(ws + O_BSUMS);
  _Float16* W16 = (_Float16*)(ws + O_W16);
  unsigned int* edg = (unsigned int*)(ws + O_EDGE);
  unsigned int* hw4 = (unsigned int*)(ws + O_HWH);
  unsigned short* part = (unsigned short*)(ws + O_PART);
  unsigned short* locc = (unsigned short*)(ws + O_LOCC);
  unsigned int* P16 = (unsigned int*)(ws + O_P);

  const int eb = (N_EDGES + 255) / 256;
  k_phist<<<NCHUNK, 256, 0, stream>>>(ei + N_EDGES, part, locc, stats);
  k_reduce<<<NB_NODE, 256, 0, stream>>>(part, cnt, dis, bsums, W, W16);
  k_scan_bsums<<<1, 256, 0, stream>>>(bsums, NB_NODE, rowptr, batch, gcnt);
  k_scan_write<<<NB_NODE, 256, 0, stream>>>(cnt, bsums, rowptr);
  k_fill<<<eb, 256, 0, stream>>>(ei, rowptr, part, locc, dis, edg);

  const int gemmb = (N_NODES + 63) / 64;              // 782
  const int gatherb = SLABS * ((N_NODES + 39) / 40);  // 10000

  for (int l = 0; l < NLAYER; ++l) {
    const float* st = (l == 0) ? nullptr : (stats + (l - 1) * 192);
    const float* ga = (l == 0) ? nullptr : (gamma + (l - 1) * 96);
    const float* be = (l == 0) ? nullptr : (beta + (l - 1) * 96);
    const float* x32 = (l == 0) ? x : nullptr;
    const unsigned int* x16 = (l == 0) ? nullptr : P16;
    k_gemm<<<gemmb, 256, 0, stream>>>(x32, x16, W16 + (size_t)l * 96 * 104,
                                      st, ga, be, hw4);
    k_gather<<<gatherb, 256, 0, stream>>>(hw4, rowptr, edg, dis, P16,
                                          stats + l * 192);
  }

  const int poolb = ((N_NODES + 31) / 32 + 7) / 8;  // 196
  k_pool<<<poolb, 192, 0, stream>>>(P16, stats + 3 * 192, gamma + 3 * 96,
                                    beta + 3 * 96, batch, pool);
  k_out<<<(N_GRAPHS * 96 + 255) / 256, 256, 0, stream>>>(pool, gcnt, out);
}

// Round 15
// 486.140 us; speedup vs baseline: 1.2161x; 1.0018x over previous
//
#include <hip/hip_runtime.h>
#include <hip/hip_bf16.h>
#include <hip/hip_fp16.h>

#define N_NODES 50000
#define N_EDGES 800000
#define DD 96
#define NLAYER 4
#define N_GRAPHS 256
#define BN_EPS 1e-5f
#define SLABS 8
#define SFEAT 12        // used halfs per slab row of hw
#define GSU 8           // uints per hw slab row (32 B)
#define AGU 6           // uints per agg slab row (24 B fp16)
#define NCHUNK 64
#define CHUNK_E (N_EDGES / NCHUNK)   // 12500
#define NB_NODE 196
#define PH_RANGES 2
#define PH_RN 25000
#define PH_HI 12500
#define PH_NE 49
#define EUNROLL 16

typedef _Float16 half8_t __attribute__((ext_vector_type(8)));
typedef float floatx4 __attribute__((ext_vector_type(4)));

// ---------------- workspace layout (units: 4-byte elements) ----------------
enum : size_t {
  O_CNT    = 0,                        // int[N_NODES]
  O_STATS  = O_CNT + N_NODES,          // float[4*192]
  O_POOL   = O_STATS + 4 * 192,        // float[N_GRAPHS*96]
  O_GCNT   = O_POOL + N_GRAPHS * DD,   // int[N_GRAPHS]
  ZERO_END = O_GCNT + N_GRAPHS,
  O_ROWPTR = ZERO_END,                 // int[N_NODES+1]
  O_DIS    = O_ROWPTR + N_NODES + 1,   // float[N_NODES]
  O_BSUMS  = O_DIS + N_NODES,          // int[256]
  O_W16    = O_BSUMS + 256,            // half[4][96][104] fp16 W^T padded
  O_EDGE   = (O_W16 + 4 * 96 * 104 / 2 + 7) & ~size_t(7),  // uint[N_EDGES+16]
  O_HWH    = (O_EDGE + N_EDGES + 16 + 7) & ~size_t(7), // uint[8][50000][8] = 12.8MB
  O_PART   = O_HWH + (size_t)SLABS * N_NODES * GSU,   // ushort[64][50000]
  O_LOCC   = O_PART + (size_t)NCHUNK * N_NODES / 2,   // ushort[N_EDGES]
  O_P      = O_LOCC + N_EDGES / 2,                    // uint[8][50000][6] fp16 agg
  WS_ELEMS = O_P + (size_t)SLABS * N_NODES * AGU      // ~35 MB
};

__device__ __forceinline__ void atomAddF(float* p, float v) {
  unsafeAtomicAdd(p, v);
}

__device__ __forceinline__ float2 h2f(unsigned int u) {
  __half2 h = *(__half2*)&u;
  return __half22float2(h);
}

// ---------------- CSR build, atomic-free (R13 proven) ----------------
__global__ __launch_bounds__(256) void k_phist(const int* __restrict__ dst,
                                               unsigned short* __restrict__ part,
                                               unsigned short* __restrict__ locc,
                                               float* __restrict__ zbase) {
  __shared__ int hist[PH_HI];
  const int b = blockIdx.x, tid = threadIdx.x;
  const int e0 = b * CHUNK_E;
  if (b == 0) {
    for (int i = tid; i < (int)(ZERO_END - O_STATS); i += 256) zbase[i] = 0.f;
  }
  int regs[PH_NE];
#pragma unroll
  for (int i = 0; i < PH_NE; ++i) {
    int e = e0 + tid + i * 256;
    regs[i] = (tid + i * 256 < CHUNK_E) ? dst[e] : -1;
  }
#pragma unroll
  for (int r = 0; r < PH_RANGES; ++r) {
    const int r0 = r * PH_RN;
    for (int i = tid; i < PH_HI; i += 256) hist[i] = 0;
    __syncthreads();
#pragma unroll
    for (int i = 0; i < PH_NE; ++i) {
      unsigned rel = (unsigned)(regs[i] - r0);
      if (rel < PH_RN) {
        int add = (rel & 1) ? (1 << 16) : 1;
        int old = atomicAdd(&hist[rel >> 1], add);
        locc[e0 + tid + i * 256] =
            (unsigned short)((rel & 1) ? (old >> 16) : (old & 0xFFFF));
      }
    }
    __syncthreads();
    for (int i = tid; i < PH_RN; i += 256) {
      int v = hist[i >> 1];
      part[(size_t)b * N_NODES + r0 + i] =
          (unsigned short)((i & 1) ? (v >> 16) : (v & 0xFFFF));
    }
    __syncthreads();
  }
}

__global__ __launch_bounds__(256) void k_reduce(unsigned short* __restrict__ part,
                                                int* __restrict__ cnt,
                                                float* __restrict__ dis,
                                                int* __restrict__ bsums,
                                                const float* __restrict__ Wg,
                                                _Float16* __restrict__ W16) {
  __shared__ int s[256];
  const int tid = threadIdx.x;
  const int n = blockIdx.x * 256 + tid;
  {
    const int gt = blockIdx.x * 256 + tid;
    const int items = 4 * 96 * 24;
    for (int i = gt; i < items; i += NB_NODE * 256) {
      int l = i / (96 * 24), rem = i % (96 * 24);
      int nn = rem / 24, k0 = (rem % 24) * 4;
      const float* wl = Wg + (size_t)l * 96 * 96;
      union { _Float16 h[4]; uint2 u; } pk;
      pk.h[0] = (_Float16)wl[(k0 + 0) * 96 + nn];
      pk.h[1] = (_Float16)wl[(k0 + 1) * 96 + nn];
      pk.h[2] = (_Float16)wl[(k0 + 2) * 96 + nn];
      pk.h[3] = (_Float16)wl[(k0 + 3) * 96 + nn];
      *(uint2*)&W16[((size_t)l * 96 + nn) * 104 + k0] = pk.u;
    }
  }
  int run = 0;
  if (n < N_NODES) {
#pragma unroll 8
    for (int b = 0; b < NCHUNK; ++b) {
      size_t idx = (size_t)b * N_NODES + n;
      int t = part[idx];
      part[idx] = (unsigned short)run;
      run += t;
    }
    cnt[n] = run;
    dis[n] = rsqrtf((float)(run + 1));
  }
  s[tid] = (n < N_NODES) ? run : 0;
  __syncthreads();
  for (int off = 128; off > 0; off >>= 1) {
    if (tid < off) s[tid] += s[tid + off];
    __syncthreads();
  }
  if (tid == 0) bsums[blockIdx.x] = s[0];
}

__device__ __forceinline__ int lbound(const int* __restrict__ a, int v) {
  int lo = 0, hi = N_NODES;
  while (lo < hi) { int m = (lo + hi) >> 1; if (a[m] < v) lo = m + 1; else hi = m; }
  return lo;
}

__global__ __launch_bounds__(256) void k_scan_bsums(int* __restrict__ bsums, int nb,
                                                    int* __restrict__ rowptr,
                                                    const int* __restrict__ batch,
                                                    int* __restrict__ gcnt) {
  __shared__ int s[256];
  int tid = threadIdx.x;
  int v = (tid < nb) ? bsums[tid] : 0;
  s[tid] = v;
  __syncthreads();
  for (int off = 1; off < 256; off <<= 1) {
    int add = (tid >= off) ? s[tid - off] : 0;
    __syncthreads();
    s[tid] += add;
    __syncthreads();
  }
  if (tid < nb) bsums[tid] = s[tid] - v;
  if (tid == 255) rowptr[N_NODES] = s[255];
  gcnt[tid] = lbound(batch, tid + 1) - lbound(batch, tid);
}

__global__ __launch_bounds__(256) void k_scan_write(const int* __restrict__ cnt,
                                                    const int* __restrict__ bsums,
                                                    int* __restrict__ rowptr) {
  __shared__ int s[256];
  int i = blockIdx.x * 256 + threadIdx.x;
  int v = (i < N_NODES) ? cnt[i] : 0;
  s[threadIdx.x] = v;
  __syncthreads();
  for (int off = 1; off < 256; off <<= 1) {
    int x = 0;
    if (threadIdx.x >= off) x = s[threadIdx.x - off];
    __syncthreads();
    s[threadIdx.x] += x;
    __syncthreads();
  }
  if (i < N_NODES) rowptr[i] = bsums[blockIdx.x] + s[threadIdx.x] - v;
}

__global__ __launch_bounds__(256) void k_fill(const int* __restrict__ ei,
                                              const int* __restrict__ rowptr,
                                              const unsigned short* __restrict__ part,
                                              const unsigned short* __restrict__ locc,
                                              const float* __restrict__ dis,
                                              unsigned int* __restrict__ edg) {
  int e = blockIdx.x * 256 + threadIdx.x;
  if (blockIdx.x == 0 && threadIdx.x < 16) edg[N_EDGES + threadIdx.x] = 0;  // pad
  if (e >= N_EDGES) return;
  int s = ei[e];
  int d = ei[N_EDGES + e];
  int chunk = e / CHUNK_E;
  int pos = rowptr[d] + (int)part[(size_t)chunk * N_NODES + d] + (int)locc[e];
  unsigned short wb = __half_as_ushort(__float2half_rn(dis[s] * dis[d]));
  edg[pos] = (unsigned int)s | ((unsigned int)wb << 16);
}

// ---------------- GEMM via MFMA fp16; X from fp32 (l=0) or fp16 agg (l>0) -----
__global__ __launch_bounds__(256) void k_gemm(const float* __restrict__ X32,
                                              const unsigned int* __restrict__ X16,
                                              const _Float16* __restrict__ Wh16,
                                              const float* __restrict__ stats,
                                              const float* __restrict__ gamma,
                                              const float* __restrict__ beta,
                                              unsigned int* __restrict__ Yu) {
  __shared__ _Float16 Xh[64 * 104];
  __shared__ _Float16 Wt[96 * 104];
  __shared__ float sA[96], sC[96];
  const int tid = threadIdx.x;
  const int row0 = blockIdx.x * 64;

  if (tid < 96) {
    if (stats) {
      float mu = stats[tid] * (1.f / N_NODES);
      float var = fmaxf(stats[96 + tid] * (1.f / N_NODES) - mu * mu, 0.f);
      float a = gamma[tid] * rsqrtf(var + BN_EPS);
      sA[tid] = a;
      sC[tid] = beta[tid] - mu * a;
    } else {
      sA[tid] = 1.f;
      sC[tid] = 0.f;
    }
  }
  for (int i = tid; i < 96 * 104 / 8; i += 256)
    *(uint4*)&Wt[i * 8] = *(const uint4*)&Wh16[i * 8];
  __syncthreads();
  const bool bn = (stats != nullptr);
  for (int i = tid; i < 64 * 24; i += 256) {
    int r = i / 24, j = i % 24;
    int c4 = j * 4;
    int gr = row0 + r;
    float4 v = make_float4(0.f, 0.f, 0.f, 0.f);
    if (gr < N_NODES) {
      if (X16) {
        int slab = j / 3, pt = j % 3;
        uint2 u = *(const uint2*)&X16[((size_t)slab * N_NODES + gr) * AGU + pt * 2];
        float2 f01 = h2f(u.x), f23 = h2f(u.y);
        v = make_float4(f01.x, f01.y, f23.x, f23.y);
      } else {
        v = *(const float4*)&X32[(size_t)gr * 96 + c4];
      }
    }
    if (bn) {
      v.x = fmaxf(v.x * sA[c4] + sC[c4], 0.f);
      v.y = fmaxf(v.y * sA[c4 + 1] + sC[c4 + 1], 0.f);
      v.z = fmaxf(v.z * sA[c4 + 2] + sC[c4 + 2], 0.f);
      v.w = fmaxf(v.w * sA[c4 + 3] + sC[c4 + 3], 0.f);
    }
    union { _Float16 h[4]; uint2 u; } pk;
    pk.h[0] = (_Float16)v.x; pk.h[1] = (_Float16)v.y;
    pk.h[2] = (_Float16)v.z; pk.h[3] = (_Float16)v.w;
    *(uint2*)&Xh[r * 104 + c4] = pk.u;
  }
  __syncthreads();

  const int w = tid >> 6, lane = tid & 63;
  const int quad = lane >> 4, l16 = lane & 15;

  half8_t a[3];
#pragma unroll
  for (int kb = 0; kb < 3; ++kb)
    a[kb] = *(const half8_t*)&Xh[(w * 16 + l16) * 104 + kb * 32 + quad * 8];

  floatx4 acc[6];
#pragma unroll
  for (int nt = 0; nt < 6; ++nt) acc[nt] = (floatx4){0.f, 0.f, 0.f, 0.f};
#pragma unroll
  for (int nt = 0; nt < 6; ++nt) {
#pragma unroll
    for (int kb = 0; kb < 3; ++kb) {
      half8_t b = *(const half8_t*)&Wt[(nt * 16 + l16) * 104 + kb * 32 + quad * 8];
      acc[nt] = __builtin_amdgcn_mfma_f32_16x16x32_f16(a[kb], b, acc[nt], 0, 0, 0);
    }
  }

  __syncthreads();
#pragma unroll
  for (int nt = 0; nt < 6; ++nt) {
#pragma unroll
    for (int reg = 0; reg < 4; ++reg) {
      int r = w * 16 + quad * 4 + reg;
      Xh[r * 104 + nt * 16 + l16] = (_Float16)acc[nt][reg];
    }
  }
  __syncthreads();
  for (int i = tid; i < 64 * 24; i += 256) {
    int r = i / 24, rem = i % 24;
    int slab = rem / 3, up = rem % 3;
    int node = row0 + r;
    if (node < N_NODES) {
      uint2 u = *(const uint2*)&Xh[r * 104 + slab * SFEAT + up * 4];
      *(uint2*)&Yu[((size_t)slab * N_NODES + node) * GSU + up * 2] = u;
    }
  }
}

// ---------------- fused aggregation + BN-stats (16-wide MLP unroll) ----------
__global__ __launch_bounds__(256) void k_gather(const unsigned int* __restrict__ hw4,
                                                const int* __restrict__ rowptr,
                                                const unsigned int* __restrict__ edg,
                                                const float* __restrict__ dis,
                                                unsigned int* __restrict__ aggu,
                                                float* __restrict__ stats) {
  __shared__ float sred[24];
  const int tid = threadIdx.x;
  const int slab = blockIdx.x & (SLABS - 1);
  const int chunk = blockIdx.x >> 3;
  const int wave = tid >> 6;
  const int lane = tid & 63;
  const int g = lane / 6;      // 0..10 (g==10 -> idle)
  const int ch = lane - g * 6; // uint index 0..5
  const int n = chunk * 40 + wave * 10 + g;
  const bool valid = (g < 10) && (n < N_NODES);
  const int nc = valid ? n : 0;

  const unsigned int* slabU = hw4 + (size_t)slab * N_NODES * GSU;

  if (tid < 24) sred[tid] = 0.f;

  const int js = valid ? rowptr[nc] : 0;
  const int je = valid ? rowptr[nc + 1] : 0;

  float a0 = 0.f, a1 = 0.f;
  if (valid) {
    float dn = dis[nc];
    float s2 = dn * dn;  // self-loop weight
    float2 f = h2f(slabU[(size_t)nc * GSU + ch]);
    a0 = f.x * s2;
    a1 = f.y * s2;
  }

  for (int j = js; j < je; j += EUNROLL) {
    unsigned int ew[EUNROLL];
    unsigned int rv[EUNROLL];
#pragma unroll
    for (int k = 0; k < EUNROLL; ++k) ew[k] = edg[j + k];  // pad-safe, no clamp
#pragma unroll
    for (int k = 0; k < EUNROLL; ++k)
      rv[k] = slabU[(size_t)(ew[k] & 0xFFFFu) * GSU + ch];
#pragma unroll
    for (int k = 0; k < EUNROLL; ++k) {
      float w = (j + k < je)
                    ? __half2float(__ushort_as_half((unsigned short)(ew[k] >> 16)))
                    : 0.f;
      float2 f = h2f(rv[k]);
      a0 = fmaf(w, f.x, a0);
      a1 = fmaf(w, f.y, a1);
    }
  }

  if (valid) {
    __half2 p = __floats2half2_rn(a0, a1);
    aggu[((size_t)slab * N_NODES + n) * AGU + ch] = *(unsigned int*)&p;
  }

  __syncthreads();
  if (valid) {
    atomicAdd(&sred[ch * 2], a0);
    atomicAdd(&sred[ch * 2 + 1], a1);
    atomicAdd(&sred[12 + ch * 2], a0 * a0);
    atomicAdd(&sred[13 + ch * 2], a1 * a1);
  }
  __syncthreads();
  if (tid < 24) {
    int c = (tid < 12) ? (slab * SFEAT + tid) : (96 + slab * SFEAT + tid - 12);
    atomAddF(&stats[c], sred[tid]);
  }
}

// ---------------- pooling: final BN+ReLU + segment-sum (fp16 agg input) -------
__global__ __launch_bounds__(192) void k_pool(const unsigned int* __restrict__ hu,
                                              const float* __restrict__ stats,
                                              const float* __restrict__ gamma,
                                              const float* __restrict__ beta,
                                              const int* __restrict__ batch,
                                              float* __restrict__ pool) {
  __shared__ float sA[96], sC[96];
  const int tid = threadIdx.x;
  if (tid < 96) {
    float mu = stats[tid] * (1.f / N_NODES);
    float var = fmaxf(stats[96 + tid] * (1.f / N_NODES) - mu * mu, 0.f);
    float a = gamma[tid] * rsqrtf(var + BN_EPS);
    sA[tid] = a;
    sC[tid] = beta[tid] - mu * a;
  }
  __syncthreads();
  const int chain = blockIdx.x * 8 + tid / 24;
  const int j = tid % 24;
  const int q4 = j * 4;
  const int slab = j / 3, pt = j % 3;
  int n0 = chain * 32;
  if (n0 >= N_NODES) return;
  int n1 = min(n0 + 32, N_NODES);
  float A0 = sA[q4], A1 = sA[q4 + 1], A2 = sA[q4 + 2], A3 = sA[q4 + 3];
  float C0 = sC[q4], C1 = sC[q4 + 1], C2 = sC[q4 + 2], C3 = sC[q4 + 3];
  const unsigned int* base = hu + (size_t)slab * N_NODES * AGU + pt * 2;
  int cur = batch[n0];
  float4 acc = make_float4(0.f, 0.f, 0.f, 0.f);
  for (int n = n0; n < n1; ++n) {
    int g = batch[n];
    if (g != cur) {
      float* p = &pool[cur * 96 + q4];
      atomAddF(p, acc.x); atomAddF(p + 1, acc.y);
      atomAddF(p + 2, acc.z); atomAddF(p + 3, acc.w);
      acc = make_float4(0.f, 0.f, 0.f, 0.f);
      cur = g;
    }
    uint2 u = *(const uint2*)&base[(size_t)n * AGU];
    float2 f01 = h2f(u.x), f23 = h2f(u.y);
    acc.x += fmaxf(f01.x * A0 + C0, 0.f);
    acc.y += fmaxf(f01.y * A1 + C1, 0.f);
    acc.z += fmaxf(f23.x * A2 + C2, 0.f);
    acc.w += fmaxf(f23.y * A3 + C3, 0.f);
  }
  float* p = &pool[cur * 96 + q4];
  atomAddF(p, acc.x); atomAddF(p + 1, acc.y);
  atomAddF(p + 2, acc.z); atomAddF(p + 3, acc.w);
}

__global__ void k_out(const float* __restrict__ pool, const int* __restrict__ gcnt,
                      float* __restrict__ out) {
  int t = blockIdx.x * blockDim.x + threadIdx.x;
  if (t >= N_GRAPHS * 96) return;
  int g = t / 96;
  int c = gcnt[g];
  if (c < 1) c = 1;
  out[t] = pool[t] / (float)c;
}

extern "C" void kernel_launch(void* const* d_in, const int* in_sizes, int n_in,
                              void* d_out, int out_size, void* d_ws, size_t ws_size,
                              hipStream_t stream) {
  const float* x     = (const float*)d_in[0];
  const int*   ei    = (const int*)d_in[1];
  const int*   batch = (const int*)d_in[2];
  const float* W     = (const float*)d_in[3];
  // d_in[4] = b : cancels exactly through BatchNorm, unused
  const float* gamma = (const float*)d_in[5];
  const float* beta  = (const float*)d_in[6];
  float* out = (float*)d_out;

  float* ws = (float*)d_ws;
  int*   cnt    = (int*)(ws + O_CNT);
  float* stats  = ws + O_STATS;
  float* pool   = ws + O_POOL;
  int*   gcnt   = (int*)(ws + O_GCNT);
  int*   rowptr = (int*)(ws + O_ROWPTR);
  float* dis    = ws + O_DIS;
  int*   bsums  = (int*)(ws + O_BSUMS);
  _Float16* W16 = (_Float16*)(ws + O_W16);
  unsigned int* edg = (unsigned int*)(ws + O_EDGE);
  unsigned int* hw4 = (unsigned int*)(ws + O_HWH);
  unsigned short* part = (unsigned short*)(ws + O_PART);
  unsigned short* locc = (unsigned short*)(ws + O_LOCC);
  unsigned int* P16 = (unsigned int*)(ws + O_P);

  const int eb = (N_EDGES + 255) / 256;
  k_phist<<<NCHUNK, 256, 0, stream>>>(ei + N_EDGES, part, locc, stats);
  k_reduce<<<NB_NODE, 256, 0, stream>>>(part, cnt, dis, bsums, W, W16);
  k_scan_bsums<<<1, 256, 0, stream>>>(bsums, NB_NODE, rowptr, batch, gcnt);
  k_scan_write<<<NB_NODE, 256, 0, stream>>>(cnt, bsums, rowptr);
  k_fill<<<eb, 256, 0, stream>>>(ei, rowptr, part, locc, dis, edg);

  const int gemmb = (N_NODES + 63) / 64;              // 782
  const int gatherb = SLABS * ((N_NODES + 39) / 40);  // 10000

  for (int l = 0; l < NLAYER; ++l) {
    const float* st = (l == 0) ? nullptr : (stats + (l - 1) * 192);
    const float* ga = (l == 0) ? nullptr : (gamma + (l - 1) * 96);
    const float* be = (l == 0) ? nullptr : (beta + (l - 1) * 96);
    const float* x32 = (l == 0) ? x : nullptr;
    const unsigned int* x16 = (l == 0) ? nullptr : P16;
    k_gemm<<<gemmb, 256, 0, stream>>>(x32, x16, W16 + (size_t)l * 96 * 104,
                                      st, ga, be, hw4);
    k_gather<<<gatherb, 256, 0, stream>>>(hw4, rowptr, edg, dis, P16,
                                          stats + l * 192);
  }

  const int poolb = ((N_NODES + 31) / 32 + 7) / 8;  // 196
  k_pool<<<poolb, 192, 0, stream>>>(P16, stats + 3 * 192, gamma + 3 * 96,
                                    beta + 3 * 96, batch, pool);
  k_out<<<(N_GRAPHS * 96 + 255) / 256, 256, 0, stream>>>(pool, gcnt, out);
}

// Round 16
// 484.086 us; speedup vs baseline: 1.2212x; 1.0042x over previous
//
#include <hip/hip_runtime.h>
#include <hip/hip_bf16.h>
#include <hip/hip_fp16.h>

#define N_NODES 50000
#define N_EDGES 800000
#define DD 96
#define NLAYER 4
#define N_GRAPHS 256
#define BN_EPS 1e-5f
#define SLABS 8
#define SFEAT 12        // used halfs per slab row of hw
#define GSU 8           // uints per hw slab row (32 B)
#define AGU 6           // uints per agg slab row (24 B fp16)
#define NCHUNK 64
#define CHUNK_E (N_EDGES / NCHUNK)   // 12500
#define NB_NODE 196
#define PH_RANGES 2
#define PH_RN 25000
#define PH_HI 12500
#define PH_NE 49
#define EUNROLL 8
#define NPW 21          // nodes per wave (3 lanes x uint2 per node)
#define NPB 84          // nodes per block

typedef _Float16 half8_t __attribute__((ext_vector_type(8)));
typedef float floatx4 __attribute__((ext_vector_type(4)));

// ---------------- workspace layout (units: 4-byte elements) ----------------
enum : size_t {
  O_CNT    = 0,                        // int[N_NODES]
  O_STATS  = O_CNT + N_NODES,          // float[4*192]
  O_POOL   = O_STATS + 4 * 192,        // float[N_GRAPHS*96]
  O_GCNT   = O_POOL + N_GRAPHS * DD,   // int[N_GRAPHS]
  ZERO_END = O_GCNT + N_GRAPHS,
  O_ROWPTR = ZERO_END,                 // int[N_NODES+1]
  O_DIS    = O_ROWPTR + N_NODES + 1,   // float[N_NODES]
  O_BSUMS  = O_DIS + N_NODES,          // int[256]
  O_W16    = O_BSUMS + 256,            // half[4][96][104] fp16 W^T padded
  O_EDGE   = (O_W16 + 4 * 96 * 104 / 2 + 7) & ~size_t(7),  // uint[N_EDGES+16]
  O_HWH    = (O_EDGE + N_EDGES + 16 + 7) & ~size_t(7), // uint[8][50000][8] = 12.8MB
  O_PART   = O_HWH + (size_t)SLABS * N_NODES * GSU,   // ushort[64][50000]
  O_LOCC   = O_PART + (size_t)NCHUNK * N_NODES / 2,   // ushort[N_EDGES]
  O_P      = O_LOCC + N_EDGES / 2,                    // uint[8][50000][6] fp16 agg
  WS_ELEMS = O_P + (size_t)SLABS * N_NODES * AGU      // ~35 MB
};

__device__ __forceinline__ void atomAddF(float* p, float v) {
  unsafeAtomicAdd(p, v);
}

__device__ __forceinline__ float2 h2f(unsigned int u) {
  __half2 h = *(__half2*)&u;
  return __half22float2(h);
}

// ---------------- CSR build, atomic-free (R13 proven) ----------------
__global__ __launch_bounds__(256) void k_phist(const int* __restrict__ dst,
                                               unsigned short* __restrict__ part,
                                               unsigned short* __restrict__ locc,
                                               float* __restrict__ zbase) {
  __shared__ int hist[PH_HI];
  const int b = blockIdx.x, tid = threadIdx.x;
  const int e0 = b * CHUNK_E;
  if (b == 0) {
    for (int i = tid; i < (int)(ZERO_END - O_STATS); i += 256) zbase[i] = 0.f;
  }
  int regs[PH_NE];
#pragma unroll
  for (int i = 0; i < PH_NE; ++i) {
    int e = e0 + tid + i * 256;
    regs[i] = (tid + i * 256 < CHUNK_E) ? dst[e] : -1;
  }
#pragma unroll
  for (int r = 0; r < PH_RANGES; ++r) {
    const int r0 = r * PH_RN;
    for (int i = tid; i < PH_HI; i += 256) hist[i] = 0;
    __syncthreads();
#pragma unroll
    for (int i = 0; i < PH_NE; ++i) {
      unsigned rel = (unsigned)(regs[i] - r0);
      if (rel < PH_RN) {
        int add = (rel & 1) ? (1 << 16) : 1;
        int old = atomicAdd(&hist[rel >> 1], add);
        locc[e0 + tid + i * 256] =
            (unsigned short)((rel & 1) ? (old >> 16) : (old & 0xFFFF));
      }
    }
    __syncthreads();
    for (int i = tid; i < PH_RN; i += 256) {
      int v = hist[i >> 1];
      part[(size_t)b * N_NODES + r0 + i] =
          (unsigned short)((i & 1) ? (v >> 16) : (v & 0xFFFF));
    }
    __syncthreads();
  }
}

__global__ __launch_bounds__(256) void k_reduce(unsigned short* __restrict__ part,
                                                int* __restrict__ cnt,
                                                float* __restrict__ dis,
                                                int* __restrict__ bsums,
                                                const float* __restrict__ Wg,
                                                _Float16* __restrict__ W16) {
  __shared__ int s[256];
  const int tid = threadIdx.x;
  const int n = blockIdx.x * 256 + tid;
  {
    const int gt = blockIdx.x * 256 + tid;
    const int items = 4 * 96 * 24;
    for (int i = gt; i < items; i += NB_NODE * 256) {
      int l = i / (96 * 24), rem = i % (96 * 24);
      int nn = rem / 24, k0 = (rem % 24) * 4;
      const float* wl = Wg + (size_t)l * 96 * 96;
      union { _Float16 h[4]; uint2 u; } pk;
      pk.h[0] = (_Float16)wl[(k0 + 0) * 96 + nn];
      pk.h[1] = (_Float16)wl[(k0 + 1) * 96 + nn];
      pk.h[2] = (_Float16)wl[(k0 + 2) * 96 + nn];
      pk.h[3] = (_Float16)wl[(k0 + 3) * 96 + nn];
      *(uint2*)&W16[((size_t)l * 96 + nn) * 104 + k0] = pk.u;
    }
  }
  int run = 0;
  if (n < N_NODES) {
#pragma unroll 8
    for (int b = 0; b < NCHUNK; ++b) {
      size_t idx = (size_t)b * N_NODES + n;
      int t = part[idx];
      part[idx] = (unsigned short)run;
      run += t;
    }
    cnt[n] = run;
    dis[n] = rsqrtf((float)(run + 1));
  }
  s[tid] = (n < N_NODES) ? run : 0;
  __syncthreads();
  for (int off = 128; off > 0; off >>= 1) {
    if (tid < off) s[tid] += s[tid + off];
    __syncthreads();
  }
  if (tid == 0) bsums[blockIdx.x] = s[0];
}

__device__ __forceinline__ int lbound(const int* __restrict__ a, int v) {
  int lo = 0, hi = N_NODES;
  while (lo < hi) { int m = (lo + hi) >> 1; if (a[m] < v) lo = m + 1; else hi = m; }
  return lo;
}

__global__ __launch_bounds__(256) void k_scan_bsums(int* __restrict__ bsums, int nb,
                                                    int* __restrict__ rowptr,
                                                    const int* __restrict__ batch,
                                                    int* __restrict__ gcnt) {
  __shared__ int s[256];
  int tid = threadIdx.x;
  int v = (tid < nb) ? bsums[tid] : 0;
  s[tid] = v;
  __syncthreads();
  for (int off = 1; off < 256; off <<= 1) {
    int add = (tid >= off) ? s[tid - off] : 0;
    __syncthreads();
    s[tid] += add;
    __syncthreads();
  }
  if (tid < nb) bsums[tid] = s[tid] - v;
  if (tid == 255) rowptr[N_NODES] = s[255];
  gcnt[tid] = lbound(batch, tid + 1) - lbound(batch, tid);
}

__global__ __launch_bounds__(256) void k_scan_write(const int* __restrict__ cnt,
                                                    const int* __restrict__ bsums,
                                                    int* __restrict__ rowptr) {
  __shared__ int s[256];
  int i = blockIdx.x * 256 + threadIdx.x;
  int v = (i < N_NODES) ? cnt[i] : 0;
  s[threadIdx.x] = v;
  __syncthreads();
  for (int off = 1; off < 256; off <<= 1) {
    int x = 0;
    if (threadIdx.x >= off) x = s[threadIdx.x - off];
    __syncthreads();
    s[threadIdx.x] += x;
    __syncthreads();
  }
  if (i < N_NODES) rowptr[i] = bsums[blockIdx.x] + s[threadIdx.x] - v;
}

__global__ __launch_bounds__(256) void k_fill(const int* __restrict__ ei,
                                              const int* __restrict__ rowptr,
                                              const unsigned short* __restrict__ part,
                                              const unsigned short* __restrict__ locc,
                                              const float* __restrict__ dis,
                                              unsigned int* __restrict__ edg) {
  int e = blockIdx.x * 256 + threadIdx.x;
  if (blockIdx.x == 0 && threadIdx.x < 16) edg[N_EDGES + threadIdx.x] = 0;  // pad
  if (e >= N_EDGES) return;
  int s = ei[e];
  int d = ei[N_EDGES + e];
  int chunk = e / CHUNK_E;
  int pos = rowptr[d] + (int)part[(size_t)chunk * N_NODES + d] + (int)locc[e];
  unsigned short wb = __half_as_ushort(__float2half_rn(dis[s] * dis[d]));
  edg[pos] = (unsigned int)s | ((unsigned int)wb << 16);
}

// ---------------- GEMM via MFMA fp16; X from fp32 (l=0) or fp16 agg (l>0) -----
__global__ __launch_bounds__(256) void k_gemm(const float* __restrict__ X32,
                                              const unsigned int* __restrict__ X16,
                                              const _Float16* __restrict__ Wh16,
                                              const float* __restrict__ stats,
                                              const float* __restrict__ gamma,
                                              const float* __restrict__ beta,
                                              unsigned int* __restrict__ Yu) {
  __shared__ _Float16 Xh[64 * 104];
  __shared__ _Float16 Wt[96 * 104];
  __shared__ float sA[96], sC[96];
  const int tid = threadIdx.x;
  const int row0 = blockIdx.x * 64;

  if (tid < 96) {
    if (stats) {
      float mu = stats[tid] * (1.f / N_NODES);
      float var = fmaxf(stats[96 + tid] * (1.f / N_NODES) - mu * mu, 0.f);
      float a = gamma[tid] * rsqrtf(var + BN_EPS);
      sA[tid] = a;
      sC[tid] = beta[tid] - mu * a;
    } else {
      sA[tid] = 1.f;
      sC[tid] = 0.f;
    }
  }
  for (int i = tid; i < 96 * 104 / 8; i += 256)
    *(uint4*)&Wt[i * 8] = *(const uint4*)&Wh16[i * 8];
  __syncthreads();
  const bool bn = (stats != nullptr);
  for (int i = tid; i < 64 * 24; i += 256) {
    int r = i / 24, j = i % 24;
    int c4 = j * 4;
    int gr = row0 + r;
    float4 v = make_float4(0.f, 0.f, 0.f, 0.f);
    if (gr < N_NODES) {
      if (X16) {
        int slab = j / 3, pt = j % 3;
        uint2 u = *(const uint2*)&X16[((size_t)slab * N_NODES + gr) * AGU + pt * 2];
        float2 f01 = h2f(u.x), f23 = h2f(u.y);
        v = make_float4(f01.x, f01.y, f23.x, f23.y);
      } else {
        v = *(const float4*)&X32[(size_t)gr * 96 + c4];
      }
    }
    if (bn) {
      v.x = fmaxf(v.x * sA[c4] + sC[c4], 0.f);
      v.y = fmaxf(v.y * sA[c4 + 1] + sC[c4 + 1], 0.f);
      v.z = fmaxf(v.z * sA[c4 + 2] + sC[c4 + 2], 0.f);
      v.w = fmaxf(v.w * sA[c4 + 3] + sC[c4 + 3], 0.f);
    }
    union { _Float16 h[4]; uint2 u; } pk;
    pk.h[0] = (_Float16)v.x; pk.h[1] = (_Float16)v.y;
    pk.h[2] = (_Float16)v.z; pk.h[3] = (_Float16)v.w;
    *(uint2*)&Xh[r * 104 + c4] = pk.u;
  }
  __syncthreads();

  const int w = tid >> 6, lane = tid & 63;
  const int quad = lane >> 4, l16 = lane & 15;

  half8_t a[3];
#pragma unroll
  for (int kb = 0; kb < 3; ++kb)
    a[kb] = *(const half8_t*)&Xh[(w * 16 + l16) * 104 + kb * 32 + quad * 8];

  floatx4 acc[6];
#pragma unroll
  for (int nt = 0; nt < 6; ++nt) acc[nt] = (floatx4){0.f, 0.f, 0.f, 0.f};
#pragma unroll
  for (int nt = 0; nt < 6; ++nt) {
#pragma unroll
    for (int kb = 0; kb < 3; ++kb) {
      half8_t b = *(const half8_t*)&Wt[(nt * 16 + l16) * 104 + kb * 32 + quad * 8];
      acc[nt] = __builtin_amdgcn_mfma_f32_16x16x32_f16(a[kb], b, acc[nt], 0, 0, 0);
    }
  }

  __syncthreads();
#pragma unroll
  for (int nt = 0; nt < 6; ++nt) {
#pragma unroll
    for (int reg = 0; reg < 4; ++reg) {
      int r = w * 16 + quad * 4 + reg;
      Xh[r * 104 + nt * 16 + l16] = (_Float16)acc[nt][reg];
    }
  }
  __syncthreads();
  for (int i = tid; i < 64 * 24; i += 256) {
    int r = i / 24, rem = i % 24;
    int slab = rem / 3, up = rem % 3;
    int node = row0 + r;
    if (node < N_NODES) {
      uint2 u = *(const uint2*)&Xh[r * 104 + slab * SFEAT + up * 4];
      *(uint2*)&Yu[((size_t)slab * N_NODES + node) * GSU + up * 2] = u;
    }
  }
}

// ---------------- fused aggregation + BN-stats (uint2 lanes, 21 nodes/wave) ---
__global__ __launch_bounds__(256) void k_gather(const unsigned int* __restrict__ hw4,
                                                const int* __restrict__ rowptr,
                                                const unsigned int* __restrict__ edg,
                                                const float* __restrict__ dis,
                                                unsigned int* __restrict__ aggu,
                                                float* __restrict__ stats) {
  __shared__ float sred[24];
  const int tid = threadIdx.x;
  const int slab = blockIdx.x & (SLABS - 1);
  const int chunk = blockIdx.x >> 3;
  const int wave = tid >> 6;
  const int lane = tid & 63;
  const int g = lane / 3;       // 0..20 (lane 63 -> g=21 idle)
  const int ch = lane - g * 3;  // uint2 index 0..2 within row
  const int n = chunk * NPB + wave * NPW + g;
  const bool valid = (g < NPW) && (n < N_NODES);
  const int nc = valid ? n : 0;

  const unsigned int* slabU = hw4 + (size_t)slab * N_NODES * GSU;

  if (tid < 24) sred[tid] = 0.f;

  const int js = valid ? rowptr[nc] : 0;
  const int je = valid ? rowptr[nc + 1] : 0;

  float a0 = 0.f, a1 = 0.f, a2 = 0.f, a3 = 0.f;
  if (valid) {
    float dn = dis[nc];
    float s2 = dn * dn;  // self-loop weight
    uint2 u = *(const uint2*)&slabU[(size_t)nc * GSU + ch * 2];
    float2 f01 = h2f(u.x), f23 = h2f(u.y);
    a0 = f01.x * s2; a1 = f01.y * s2; a2 = f23.x * s2; a3 = f23.y * s2;
  }

  for (int j = js; j < je; j += EUNROLL) {
    unsigned int ew[EUNROLL];
    uint2 rv[EUNROLL];
#pragma unroll
    for (int k = 0; k < EUNROLL; ++k) ew[k] = edg[j + k];  // pad-safe
#pragma unroll
    for (int k = 0; k < EUNROLL; ++k)
      rv[k] = *(const uint2*)&slabU[(size_t)(ew[k] & 0xFFFFu) * GSU + ch * 2];
#pragma unroll
    for (int k = 0; k < EUNROLL; ++k) {
      float w = (j + k < je)
                    ? __half2float(__ushort_as_half((unsigned short)(ew[k] >> 16)))
                    : 0.f;
      float2 f01 = h2f(rv[k].x), f23 = h2f(rv[k].y);
      a0 = fmaf(w, f01.x, a0);
      a1 = fmaf(w, f01.y, a1);
      a2 = fmaf(w, f23.x, a2);
      a3 = fmaf(w, f23.y, a3);
    }
  }

  if (valid) {
    __half2 p01 = __floats2half2_rn(a0, a1);
    __half2 p23 = __floats2half2_rn(a2, a3);
    uint2 o;
    o.x = *(unsigned int*)&p01;
    o.y = *(unsigned int*)&p23;
    *(uint2*)&aggu[((size_t)slab * N_NODES + n) * AGU + ch * 2] = o;
  }

  __syncthreads();
  if (valid) {
    atomicAdd(&sred[ch * 4 + 0], a0);
    atomicAdd(&sred[ch * 4 + 1], a1);
    atomicAdd(&sred[ch * 4 + 2], a2);
    atomicAdd(&sred[ch * 4 + 3], a3);
    atomicAdd(&sred[12 + ch * 4 + 0], a0 * a0);
    atomicAdd(&sred[12 + ch * 4 + 1], a1 * a1);
    atomicAdd(&sred[12 + ch * 4 + 2], a2 * a2);
    atomicAdd(&sred[12 + ch * 4 + 3], a3 * a3);
  }
  __syncthreads();
  if (tid < 24) {
    int c = (tid < 12) ? (slab * SFEAT + tid) : (96 + slab * SFEAT + tid - 12);
    atomAddF(&stats[c], sred[tid]);
  }
}

// ---------------- pooling: final BN+ReLU + segment-sum (fp16 agg input) -------
__global__ __launch_bounds__(192) void k_pool(const unsigned int* __restrict__ hu,
                                              const float* __restrict__ stats,
                                              const float* __restrict__ gamma,
                                              const float* __restrict__ beta,
                                              const int* __restrict__ batch,
                                              float* __restrict__ pool) {
  __shared__ float sA[96], sC[96];
  const int tid = threadIdx.x;
  if (tid < 96) {
    float mu = stats[tid] * (1.f / N_NODES);
    float var = fmaxf(stats[96 + tid] * (1.f / N_NODES) - mu * mu, 0.f);
    float a = gamma[tid] * rsqrtf(var + BN_EPS);
    sA[tid] = a;
    sC[tid] = beta[tid] - mu * a;
  }
  __syncthreads();
  const int chain = blockIdx.x * 8 + tid / 24;
  const int j = tid % 24;
  const int q4 = j * 4;
  const int slab = j / 3, pt = j % 3;
  int n0 = chain * 32;
  if (n0 >= N_NODES) return;
  int n1 = min(n0 + 32, N_NODES);
  float A0 = sA[q4], A1 = sA[q4 + 1], A2 = sA[q4 + 2], A3 = sA[q4 + 3];
  float C0 = sC[q4], C1 = sC[q4 + 1], C2 = sC[q4 + 2], C3 = sC[q4 + 3];
  const unsigned int* base = hu + (size_t)slab * N_NODES * AGU + pt * 2;
  int cur = batch[n0];
  float4 acc = make_float4(0.f, 0.f, 0.f, 0.f);
  for (int n = n0; n < n1; ++n) {
    int g = batch[n];
    if (g != cur) {
      float* p = &pool[cur * 96 + q4];
      atomAddF(p, acc.x); atomAddF(p + 1, acc.y);
      atomAddF(p + 2, acc.z); atomAddF(p + 3, acc.w);
      acc = make_float4(0.f, 0.f, 0.f, 0.f);
      cur = g;
    }
    uint2 u = *(const uint2*)&base[(size_t)n * AGU];
    float2 f01 = h2f(u.x), f23 = h2f(u.y);
    acc.x += fmaxf(f01.x * A0 + C0, 0.f);
    acc.y += fmaxf(f01.y * A1 + C1, 0.f);
    acc.z += fmaxf(f23.x * A2 + C2, 0.f);
    acc.w += fmaxf(f23.y * A3 + C3, 0.f);
  }
  float* p = &pool[cur * 96 + q4];
  atomAddF(p, acc.x); atomAddF(p + 1, acc.y);
  atomAddF(p + 2, acc.z); atomAddF(p + 3, acc.w);
}

__global__ void k_out(const float* __restrict__ pool, const int* __restrict__ gcnt,
                      float* __restrict__ out) {
  int t = blockIdx.x * blockDim.x + threadIdx.x;
  if (t >= N_GRAPHS * 96) return;
  int g = t / 96;
  int c = gcnt[g];
  if (c < 1) c = 1;
  out[t] = pool[t] / (float)c;
}

extern "C" void kernel_launch(void* const* d_in, const int* in_sizes, int n_in,
                              void* d_out, int out_size, void* d_ws, size_t ws_size,
                              hipStream_t stream) {
  const float* x     = (const float*)d_in[0];
  const int*   ei    = (const int*)d_in[1];
  const int*   batch = (const int*)d_in[2];
  const float* W     = (const float*)d_in[3];
  // d_in[4] = b : cancels exactly through BatchNorm, unused
  const float* gamma = (const float*)d_in[5];
  const float* beta  = (const float*)d_in[6];
  float* out = (float*)d_out;

  float* ws = (float*)d_ws;
  int*   cnt    = (int*)(ws + O_CNT);
  float* stats  = ws + O_STATS;
  float* pool   = ws + O_POOL;
  int*   gcnt   = (int*)(ws + O_GCNT);
  int*   rowptr = (int*)(ws + O_ROWPTR);
  float* dis    = ws + O_DIS;
  int*   bsums  = (int*)(ws + O_BSUMS);
  _Float16* W16 = (_Float16*)(ws + O_W16);
  unsigned int* edg = (unsigned int*)(ws + O_EDGE);
  unsigned int* hw4 = (unsigned int*)(ws + O_HWH);
  unsigned short* part = (unsigned short*)(ws + O_PART);
  unsigned short* locc = (unsigned short*)(ws + O_LOCC);
  unsigned int* P16 = (unsigned int*)(ws + O_P);

  const int eb = (N_EDGES + 255) / 256;
  k_phist<<<NCHUNK, 256, 0, stream>>>(ei + N_EDGES, part, locc, stats);
  k_reduce<<<NB_NODE, 256, 0, stream>>>(part, cnt, dis, bsums, W, W16);
  k_scan_bsums<<<1, 256, 0, stream>>>(bsums, NB_NODE, rowptr, batch, gcnt);
  k_scan_write<<<NB_NODE, 256, 0, stream>>>(cnt, bsums, rowptr);
  k_fill<<<eb, 256, 0, stream>>>(ei, rowptr, part, locc, dis, edg);

  const int gemmb = (N_NODES + 63) / 64;                   // 782
  const int gatherb = SLABS * ((N_NODES + NPB - 1) / NPB); // 8 * 596 = 4768

  for (int l = 0; l < NLAYER; ++l) {
    const float* st = (l == 0) ? nullptr : (stats + (l - 1) * 192);
    const float* ga = (l == 0) ? nullptr : (gamma + (l - 1) * 96);
    const float* be = (l == 0) ? nullptr : (beta + (l - 1) * 96);
    const float* x32 = (l == 0) ? x : nullptr;
    const unsigned int* x16 = (l == 0) ? nullptr : P16;
    k_gemm<<<gemmb, 256, 0, stream>>>(x32, x16, W16 + (size_t)l * 96 * 104,
                                      st, ga, be, hw4);
    k_gather<<<gatherb, 256, 0, stream>>>(hw4, rowptr, edg, dis, P16,
                                          stats + l * 192);
  }

  const int poolb = ((N_NODES + 31) / 32 + 7) / 8;  // 196
  k_pool<<<poolb, 192, 0, stream>>>(P16, stats + 3 * 192, gamma + 3 * 96,
                                    beta + 3 * 96, batch, pool);
  k_out<<<(N_GRAPHS * 96 + 255) / 256, 256, 0, stream>>>(pool, gcnt, out);
}